// Round 1
// baseline (6500.542 us; speedup 1.0000x reference)
//
#include <hip/hip_runtime.h>

// EGNN conv: N=50000 nodes, E=800000 edges, IN_C=HID=OUT_C=64.
// Round 1: correct fp32 baseline, wave-per-edge, LDS-staged transposed weights,
// __shfl broadcast of inputs, atomicAdd segment-sum into d_ws.

#define NN 50000
#define NE 800000

__device__ __forceinline__ float silu_f(float x) {
    return x / (1.0f + __expf(-x));
}

// Partial dot: lane j accumulates sum_k shfl(x,k) * wrow[k], k = 0..63.
// wrow points at this lane's transposed weight row (16 float4s).
__device__ __forceinline__ float wave_matvec64(const float4* __restrict__ wrow, float x) {
    float a0 = 0.f, a1 = 0.f, a2 = 0.f, a3 = 0.f;
#pragma unroll
    for (int q = 0; q < 16; ++q) {
        float4 w = wrow[q];
        a0 += __shfl(x, 4 * q + 0, 64) * w.x;
        a1 += __shfl(x, 4 * q + 1, 64) * w.y;
        a2 += __shfl(x, 4 * q + 2, 64) * w.z;
        a3 += __shfl(x, 4 * q + 3, 64) * w.w;
    }
    return (a0 + a1) + (a2 + a3);
}

__global__ __launch_bounds__(256, 2) void egnn_edge_kernel(
    const float* __restrict__ h, const float* __restrict__ pos,
    const int* __restrict__ ei,  // [2][E] int32
    const float* __restrict__ We1, const float* __restrict__ be1,
    const float* __restrict__ We2, const float* __restrict__ be2,
    const float* __restrict__ Wc1, const float* __restrict__ bc1,
    const float* __restrict__ Wc2, const float* __restrict__ bc2,
    float* __restrict__ msg_agg, float* __restrict__ coord_agg)
{
    // Transposed weights in LDS: row j = column j of W. Row strides 132/68 floats
    // keep float4 rows 16B-aligned with max bank spread (odd multiple of 4).
    __shared__ __align__(16) float sWe1T[64][132];  // 129 used
    __shared__ __align__(16) float sWe2T[64][68];   // 64 used
    __shared__ __align__(16) float sWc1T[64][68];
    __shared__ float sWc2[64];
    __shared__ float sbe1[64], sbe2[64], sbc1[64];

    const int tid = threadIdx.x;
    for (int i = tid; i < 129 * 64; i += 256) sWe1T[i & 63][i >> 6] = We1[i];
    for (int i = tid; i < 64 * 64; i += 256) {
        const int k = i >> 6, j = i & 63;
        sWe2T[j][k] = We2[i];
        sWc1T[j][k] = Wc1[i];
    }
    if (tid < 64) {
        sWc2[tid] = Wc2[tid];
        sbe1[tid] = be1[tid];
        sbe2[tid] = be2[tid];
        sbc1[tid] = bc1[tid];
    }
    const float bc2v = bc2[0];
    __syncthreads();

    const int lane  = tid & 63;
    const int wave  = blockIdx.x * 4 + (tid >> 6);
    const int nwave = gridDim.x * 4;

    const float4* w1 = (const float4*)(&sWe1T[lane][0]);
    const float4* w2 = (const float4*)(&sWe2T[lane][0]);
    const float4* wc = (const float4*)(&sWc1T[lane][0]);
    const float w1d  = sWe1T[lane][128];  // dist_sq weight (k = 128)
    const float b1v = sbe1[lane], b2v = sbe2[lane], bc1v = sbc1[lane];
    const float wc2v = sWc2[lane];

    for (int e = wave; e < NE; e += nwave) {
        const int row = ei[e];
        const int col = ei[NE + e];

        const float hr = h[(size_t)row * 64 + lane];
        const float hc = h[(size_t)col * 64 + lane];
        const float rx = pos[row * 3 + 0] - pos[col * 3 + 0];
        const float ry = pos[row * 3 + 1] - pos[col * 3 + 1];
        const float rz = pos[row * 3 + 2] - pos[col * 3 + 2];
        const float dsq = rx * rx + ry * ry + rz * rz;

        // layer e1: edge_input = [h[row], h[col], dsq] (129) -> 64, SiLU
        float m = wave_matvec64(w1, hr) + wave_matvec64(w1 + 16, hc) + dsq * w1d + b1v;
        m = silu_f(m);

        // layer e2: 64 -> 64, SiLU
        float msg = wave_matvec64(w2, m) + b2v;
        msg = silu_f(msg);

        // coord head: silu(msg @ Wc1 + bc1) @ Wc2 + bc2
        float t = wave_matvec64(wc, msg) + bc1v;
        t = silu_f(t);
        float cw = t * wc2v;
#pragma unroll
        for (int off = 32; off > 0; off >>= 1) cw += __shfl_xor(cw, off, 64);
        cw += bc2v;

        // segment sums (row-indexed)
        atomicAdd(&msg_agg[(size_t)row * 64 + lane], msg);
        if (lane < 3) {
            const float r3 = (lane == 0) ? rx : ((lane == 1) ? ry : rz);
            atomicAdd(&coord_agg[row * 3 + lane], r3 * cw);
        }
    }
}

__global__ __launch_bounds__(256, 2) void egnn_node_kernel(
    const float* __restrict__ h, const float* __restrict__ pos,
    const float* __restrict__ msg_agg, const float* __restrict__ coord_agg,
    const float* __restrict__ Wn1, const float* __restrict__ bn1,
    const float* __restrict__ Wn2, const float* __restrict__ bn2,
    float* __restrict__ h_out, float* __restrict__ pos_out)
{
    __shared__ __align__(16) float sWn1T[64][132];  // 128 used
    __shared__ __align__(16) float sWn2T[64][68];
    __shared__ float sbn1[64], sbn2[64];

    const int tid = threadIdx.x;
    for (int i = tid; i < 128 * 64; i += 256) sWn1T[i & 63][i >> 6] = Wn1[i];
    for (int i = tid; i < 64 * 64; i += 256) sWn2T[i & 63][i >> 6] = Wn2[i];
    if (tid < 64) { sbn1[tid] = bn1[tid]; sbn2[tid] = bn2[tid]; }
    __syncthreads();

    const int lane  = tid & 63;
    const int wave  = blockIdx.x * 4 + (tid >> 6);
    const int nwave = gridDim.x * 4;

    const float4* w1 = (const float4*)(&sWn1T[lane][0]);
    const float4* w2 = (const float4*)(&sWn2T[lane][0]);
    const float b1v = sbn1[lane], b2v = sbn2[lane];

    for (int n = wave; n < NN; n += nwave) {
        const float hv = h[(size_t)n * 64 + lane];
        const float mv = msg_agg[(size_t)n * 64 + lane];

        float t = wave_matvec64(w1, hv) + wave_matvec64(w1 + 16, mv) + b1v;
        t = silu_f(t);
        float o = wave_matvec64(w2, t) + b2v;

        h_out[(size_t)n * 64 + lane] = o;
        if (lane < 3) pos_out[n * 3 + lane] = pos[n * 3 + lane] + coord_agg[n * 3 + lane];
    }
}

extern "C" void kernel_launch(void* const* d_in, const int* in_sizes, int n_in,
                              void* d_out, int out_size, void* d_ws, size_t ws_size,
                              hipStream_t stream) {
    const float* h   = (const float*)d_in[0];
    const float* pos = (const float*)d_in[1];
    const int*   ei  = (const int*)d_in[2];
    const float* We1 = (const float*)d_in[3];
    const float* be1 = (const float*)d_in[4];
    const float* We2 = (const float*)d_in[5];
    const float* be2 = (const float*)d_in[6];
    const float* Wc1 = (const float*)d_in[7];
    const float* bc1 = (const float*)d_in[8];
    const float* Wc2 = (const float*)d_in[9];
    const float* bc2 = (const float*)d_in[10];
    const float* Wn1 = (const float*)d_in[11];
    const float* bn1 = (const float*)d_in[12];
    const float* Wn2 = (const float*)d_in[13];
    const float* bn2 = (const float*)d_in[14];

    float* msg_agg   = (float*)d_ws;                 // [N,64]
    float* coord_agg = msg_agg + (size_t)NN * 64;    // [N,3]
    float* h_out   = (float*)d_out;                  // [N,64]
    float* pos_out = h_out + (size_t)NN * 64;        // [N,3]

    hipMemsetAsync(d_ws, 0, (size_t)NN * 67 * sizeof(float), stream);
    egnn_edge_kernel<<<512, 256, 0, stream>>>(h, pos, ei, We1, be1, We2, be2,
                                              Wc1, bc1, Wc2, bc2, msg_agg, coord_agg);
    egnn_node_kernel<<<768, 256, 0, stream>>>(h, pos, msg_agg, coord_agg,
                                              Wn1, bn1, Wn2, bn2, h_out, pos_out);
}

// Round 2
// 3936.692 us; speedup vs baseline: 1.6513x; 1.6513x over previous
//
#include <hip/hip_runtime.h>

// EGNN conv: N=50000 nodes, E=800000 edges, IN_C=HID=OUT_C=64.
// Round 2: CSR-sort edges by row (on-device counting sort), wave-per-row edge
// kernel with register accumulation -> plain stores (no f32 atomics), 4-edge
// inner batching to share LDS weight reads, hoisted h[row] half of layer e1.
// Round-1 evidence: edge kernel 6.34ms, VALUBusy 8.8%, hbm_bytes 11.1GB
// (gather L2-thrash x8 XCDs + 51M scattered atomics). This round attacks
// traffic, not compute.

#define NN 50000
#define NE 800000

__device__ __forceinline__ float silu_f(float x) {
    return x / (1.0f + __expf(-x));
}

// Lane j accumulates acc[j_edge] += sum_k shfl(x,k) * wrow[k] for EC edges,
// sharing each LDS float4 read across the EC edges.
// LDS row stride is an odd multiple of 4 floats (132/68) -> b128 quad-bank
// group of lane j at chunk q is (j+q) mod 8: fully balanced, no conflicts.
template <int EC>
__device__ __forceinline__ void wave_matvec64_xN(const float4* __restrict__ wrow,
                                                 const float* x, float* acc) {
#pragma unroll
    for (int q = 0; q < 16; ++q) {
        float4 w = wrow[q];
#pragma unroll
        for (int j = 0; j < EC; ++j) {
            acc[j] += __shfl(x[j], 4 * q + 0, 64) * w.x;
            acc[j] += __shfl(x[j], 4 * q + 1, 64) * w.y;
            acc[j] += __shfl(x[j], 4 * q + 2, 64) * w.z;
            acc[j] += __shfl(x[j], 4 * q + 3, 64) * w.w;
        }
    }
}

// ---------------- preprocessing: counting sort by row ----------------

__global__ void hist_kernel(const int* __restrict__ ei, int* __restrict__ deg) {
    int i = blockIdx.x * blockDim.x + threadIdx.x;
    const int stride = gridDim.x * blockDim.x;
    for (; i < NE; i += stride) atomicAdd(&deg[ei[i]], 1);
}

// Single-block exclusive scan of deg[0..NN) -> row_ptr[0..NN], cursor copy.
// deg and cursor are the SAME array (in-place rewrite; each thread touches
// only its own chunk).
__global__ void scan_kernel(int* __restrict__ deg_cursor, int* __restrict__ row_ptr) {
    constexpr int C = 49;  // 1024*49 = 50176 >= 50000
    __shared__ int part[1024];
    const int t = threadIdx.x;
    const int base = t * C;
    int local[C];
    int s = 0;
#pragma unroll
    for (int i = 0; i < C; ++i) {
        int v = (base + i < NN) ? deg_cursor[base + i] : 0;
        local[i] = v;
        s += v;
    }
    part[t] = s;
    __syncthreads();
    for (int d = 1; d < 1024; d <<= 1) {
        int v = (t >= d) ? part[t - d] : 0;
        __syncthreads();
        part[t] += v;
        __syncthreads();
    }
    int run = part[t] - s;  // exclusive prefix of this chunk
#pragma unroll
    for (int i = 0; i < C; ++i) {
        const int idx = base + i;
        if (idx < NN) {
            row_ptr[idx] = run;
            deg_cursor[idx] = run;  // cursor for scatter
            run += local[i];
        }
    }
    if (t == 1023) row_ptr[NN] = part[1023];  // == NE
}

__global__ void scatter_kernel(const int* __restrict__ ei, int* __restrict__ cursor,
                               int* __restrict__ sorted_col) {
    int i = blockIdx.x * blockDim.x + threadIdx.x;
    const int stride = gridDim.x * blockDim.x;
    for (; i < NE; i += stride) {
        const int r = ei[i];
        const int c = ei[NE + i];
        const int p = atomicAdd(&cursor[r], 1);
        sorted_col[p] = c;
    }
}

// ---------------- edge kernel: wave per row ----------------

template <int EC>
__device__ __forceinline__ void do_edges(
    const int* __restrict__ sorted_col, int e,
    const float* __restrict__ h, const float* __restrict__ pos,
    float prx, float pry, float prz, float a1r, float w1d,
    float b1v, float b2v, float bc1v, float wc2v, float bc2v,
    const float4* w1c, const float4* w2, const float4* wc,
    int lane, float& msg, float& cx, float& cy, float& cz)
{
    int c[EC];
    float hc[EC], rx[EC], ry[EC], rz[EC];
#pragma unroll
    for (int j = 0; j < EC; ++j) c[j] = sorted_col[e + j];
#pragma unroll
    for (int j = 0; j < EC; ++j) hc[j] = h[(size_t)c[j] * 64 + lane];
#pragma unroll
    for (int j = 0; j < EC; ++j) {
        rx[j] = prx - pos[c[j] * 3 + 0];
        ry[j] = pry - pos[c[j] * 3 + 1];
        rz[j] = prz - pos[c[j] * 3 + 2];
    }
    // layer e1: a1r (h[row] half, hoisted per row) + h[col] half + dsq*w1d + b1
    float m[EC];
#pragma unroll
    for (int j = 0; j < EC; ++j)
        m[j] = a1r + b1v + (rx[j] * rx[j] + ry[j] * ry[j] + rz[j] * rz[j]) * w1d;
    wave_matvec64_xN<EC>(w1c, hc, m);
#pragma unroll
    for (int j = 0; j < EC; ++j) m[j] = silu_f(m[j]);
    // layer e2
    float mg[EC];
#pragma unroll
    for (int j = 0; j < EC; ++j) mg[j] = b2v;
    wave_matvec64_xN<EC>(w2, m, mg);
#pragma unroll
    for (int j = 0; j < EC; ++j) mg[j] = silu_f(mg[j]);
    // coord head
    float t[EC];
#pragma unroll
    for (int j = 0; j < EC; ++j) t[j] = bc1v;
    wave_matvec64_xN<EC>(wc, mg, t);
#pragma unroll
    for (int j = 0; j < EC; ++j) {
        float cw = silu_f(t[j]) * wc2v;
#pragma unroll
        for (int off = 32; off > 0; off >>= 1) cw += __shfl_xor(cw, off, 64);
        cw += bc2v;
        msg += mg[j];
        cx += rx[j] * cw;
        cy += ry[j] * cw;
        cz += rz[j] * cw;
    }
}

__global__ __launch_bounds__(256, 2) void egnn_edge_kernel(
    const float* __restrict__ h, const float* __restrict__ pos,
    const int* __restrict__ row_ptr, const int* __restrict__ sorted_col,
    const float* __restrict__ We1, const float* __restrict__ be1,
    const float* __restrict__ We2, const float* __restrict__ be2,
    const float* __restrict__ Wc1, const float* __restrict__ bc1,
    const float* __restrict__ Wc2, const float* __restrict__ bc2,
    float* __restrict__ msg_agg, float* __restrict__ pos_out)
{
    __shared__ __align__(16) float sWe1T[64][132];  // 129 used
    __shared__ __align__(16) float sWe2T[64][68];
    __shared__ __align__(16) float sWc1T[64][68];
    __shared__ float sWc2[64];
    __shared__ float sbe1[64], sbe2[64], sbc1[64];

    const int tid = threadIdx.x;
    for (int i = tid; i < 129 * 64; i += 256) sWe1T[i & 63][i >> 6] = We1[i];
    for (int i = tid; i < 64 * 64; i += 256) {
        const int k = i >> 6, j = i & 63;
        sWe2T[j][k] = We2[i];
        sWc1T[j][k] = Wc1[i];
    }
    if (tid < 64) {
        sWc2[tid] = Wc2[tid];
        sbe1[tid] = be1[tid];
        sbe2[tid] = be2[tid];
        sbc1[tid] = bc1[tid];
    }
    const float bc2v = bc2[0];
    __syncthreads();

    const int lane  = tid & 63;
    const int wave  = blockIdx.x * 4 + (tid >> 6);
    const int nwave = gridDim.x * 4;

    const float4* w1  = (const float4*)(&sWe1T[lane][0]);
    const float4* w1c = w1 + 16;  // h[col] half (k=64..127)
    const float4* w2  = (const float4*)(&sWe2T[lane][0]);
    const float4* wc  = (const float4*)(&sWc1T[lane][0]);
    const float w1d   = sWe1T[lane][128];  // dist_sq weight (k=128)
    const float b1v = sbe1[lane], b2v = sbe2[lane], bc1v = sbc1[lane];
    const float wc2v = sWc2[lane];

    for (int r = wave; r < NN; r += nwave) {
        const int es = row_ptr[r];
        const int ee = row_ptr[r + 1];
        const float hr  = h[(size_t)r * 64 + lane];
        const float prx = pos[r * 3 + 0];
        const float pry = pos[r * 3 + 1];
        const float prz = pos[r * 3 + 2];
        // hoisted h[row] half of layer e1 (once per row, not per edge)
        float a1r;
        {
            float x1[1] = {hr};
            float a1[1] = {0.f};
            wave_matvec64_xN<1>(w1, x1, a1);
            a1r = a1[0];
        }
        float msg = 0.f, cx = 0.f, cy = 0.f, cz = 0.f;
        int e = es;
        for (; e + 4 <= ee; e += 4)
            do_edges<4>(sorted_col, e, h, pos, prx, pry, prz, a1r, w1d,
                        b1v, b2v, bc1v, wc2v, bc2v, w1c, w2, wc, lane, msg, cx, cy, cz);
        for (; e < ee; ++e)
            do_edges<1>(sorted_col, e, h, pos, prx, pry, prz, a1r, w1d,
                        b1v, b2v, bc1v, wc2v, bc2v, w1c, w2, wc, lane, msg, cx, cy, cz);

        msg_agg[(size_t)r * 64 + lane] = msg;  // plain store: row owned by this wave
        if (lane < 3) {
            const float pv = (lane == 0) ? prx + cx : ((lane == 1) ? pry + cy : prz + cz);
            pos_out[r * 3 + lane] = pv;
        }
    }
}

// ---------------- node kernel ----------------

__global__ __launch_bounds__(256, 2) void egnn_node_kernel(
    const float* __restrict__ h, const float* __restrict__ msg_agg,
    const float* __restrict__ Wn1, const float* __restrict__ bn1,
    const float* __restrict__ Wn2, const float* __restrict__ bn2,
    float* __restrict__ h_out)
{
    __shared__ __align__(16) float sWn1T[64][132];  // 128 used
    __shared__ __align__(16) float sWn2T[64][68];
    __shared__ float sbn1[64], sbn2[64];

    const int tid = threadIdx.x;
    for (int i = tid; i < 128 * 64; i += 256) sWn1T[i & 63][i >> 6] = Wn1[i];
    for (int i = tid; i < 64 * 64; i += 256) sWn2T[i & 63][i >> 6] = Wn2[i];
    if (tid < 64) { sbn1[tid] = bn1[tid]; sbn2[tid] = bn2[tid]; }
    __syncthreads();

    const int lane  = tid & 63;
    const int wave  = blockIdx.x * 4 + (tid >> 6);
    const int nwave = gridDim.x * 4;

    const float4* w1 = (const float4*)(&sWn1T[lane][0]);
    const float4* w2 = (const float4*)(&sWn2T[lane][0]);
    const float b1v = sbn1[lane], b2v = sbn2[lane];

    for (int n = wave; n < NN; n += nwave) {
        const float hv = h[(size_t)n * 64 + lane];
        const float mv = msg_agg[(size_t)n * 64 + lane];
        float x2[2] = {hv, mv};
        float t2[2] = {b1v * 0.5f, b1v * 0.5f};  // split bias; summed below
        // layer n1: [h | msg] (128) -> 64
        float acc[1] = {b1v};
        {
            float xa[1] = {hv};
            float aa[1] = {0.f};
            wave_matvec64_xN<1>(w1, xa, aa);
            float xb[1] = {mv};
            float ab[1] = {0.f};
            wave_matvec64_xN<1>(w1 + 16, xb, ab);
            acc[0] = b1v + aa[0] + ab[0];
        }
        (void)x2; (void)t2;
        const float t = silu_f(acc[0]);
        float o[1] = {b2v};
        {
            float xt[1] = {t};
            float ao[1] = {0.f};
            wave_matvec64_xN<1>(w2, xt, ao);
            o[0] = b2v + ao[0];
        }
        h_out[(size_t)n * 64 + lane] = o[0];
    }
}

// ---------------- launch ----------------

extern "C" void kernel_launch(void* const* d_in, const int* in_sizes, int n_in,
                              void* d_out, int out_size, void* d_ws, size_t ws_size,
                              hipStream_t stream) {
    const float* h   = (const float*)d_in[0];
    const float* pos = (const float*)d_in[1];
    const int*   ei  = (const int*)d_in[2];
    const float* We1 = (const float*)d_in[3];
    const float* be1 = (const float*)d_in[4];
    const float* We2 = (const float*)d_in[5];
    const float* be2 = (const float*)d_in[6];
    const float* Wc1 = (const float*)d_in[7];
    const float* bc1 = (const float*)d_in[8];
    const float* Wc2 = (const float*)d_in[9];
    const float* bc2 = (const float*)d_in[10];
    const float* Wn1 = (const float*)d_in[11];
    const float* bn1 = (const float*)d_in[12];
    const float* Wn2 = (const float*)d_in[13];
    const float* bn2 = (const float*)d_in[14];

    // workspace layout (~16.4 MB)
    float* msg_agg    = (float*)d_ws;                    // [N,64] f32
    int*   sorted_col = (int*)(msg_agg + (size_t)NN * 64);  // [E]
    int*   row_ptr    = sorted_col + NE;                 // [N+1]
    int*   deg_cursor = row_ptr + NN + 1;                // [N]

    float* h_out   = (float*)d_out;                  // [N,64]
    float* pos_out = h_out + (size_t)NN * 64;        // [N,3]

    // counting sort by row
    hipMemsetAsync(deg_cursor, 0, (size_t)NN * sizeof(int), stream);
    hist_kernel<<<1024, 256, 0, stream>>>(ei, deg_cursor);
    scan_kernel<<<1, 1024, 0, stream>>>(deg_cursor, row_ptr);
    scatter_kernel<<<1024, 256, 0, stream>>>(ei, deg_cursor, sorted_col);

    egnn_edge_kernel<<<512, 256, 0, stream>>>(h, pos, row_ptr, sorted_col,
                                              We1, be1, We2, be2, Wc1, bc1, Wc2, bc2,
                                              msg_agg, pos_out);
    egnn_node_kernel<<<768, 256, 0, stream>>>(h, msg_agg, Wn1, bn1, Wn2, bn2, h_out);
}

// Round 3
// 546.189 us; speedup vs baseline: 11.9016x; 7.2076x over previous
//
#include <hip/hip_runtime.h>

// EGNN conv: N=50000 nodes, E=800000 edges, IN_C=HID=OUT_C=64.
// Round 3: MFMA rewrite. Layer e1 is linear in h[row] and h[col] separately ->
// precompute per-node tables a1r = h@We1[0:64]+be1, a1c = h@We1[64:128] (bf16).
// Edge kernel: 64-edge tiles, elementwise m = silu(a1r+a1c+dsq*w1d), then two
// 64x64x64 bf16 MFMA GEMMs (We2, Wc1) per tile; run-tracking atomic aggregation
// (CSR-sorted edges). msg_agg accumulates in d_out's h_out region; node MLP is
// an MFMA GEMM that reads msg_agg and overwrites h_out tile-in-place.
// Round-2 evidence: shfl-matvec = ds_bpermute storm on LDS pipe + VGPR spills
// (WRITE_SIZE 2.2GB); VALUBusy 10%. This round moves matmuls to the MFMA pipe.

#define NN 50000
#define NE 800000

typedef __attribute__((ext_vector_type(8))) short bf16x8;
typedef __attribute__((ext_vector_type(4))) float f32x4;

#define MFMA16(a, b, c) __builtin_amdgcn_mfma_f32_16x16x32_bf16(a, b, c, 0, 0, 0)

__device__ __forceinline__ unsigned short f2b(float x) {
    union { float f; unsigned u; } v; v.f = x;
    return (unsigned short)((v.u + 0x7fffu + ((v.u >> 16) & 1u)) >> 16);
}
__device__ __forceinline__ float b2f(unsigned short b) {
    union { unsigned u; float f; } v; v.u = ((unsigned)b) << 16; return v.f;
}
__device__ __forceinline__ float silu_f(float x) {
    return x / (1.0f + __expf(-x));
}

// B-frag (16x16x32, K x N, row-major W[K][64]): lane holds n=n0+(l&15), k=kb..kb+7
__device__ __forceinline__ bf16x8 load_bfrag(const float* __restrict__ W,
                                             int k0, int n0, int li, int lg) {
    const int n = n0 + li;
    const int kb = k0 + (lg << 3);
    bf16x8 v;
#pragma unroll
    for (int j = 0; j < 8; ++j) v[j] = (short)f2b(W[(kb + j) * 64 + n]);
    return v;
}

// ---------------- preprocessing: counting sort by row ----------------

__global__ void hist_kernel(const int* __restrict__ ei, int* __restrict__ deg) {
    int i = blockIdx.x * blockDim.x + threadIdx.x;
    const int stride = gridDim.x * blockDim.x;
    for (; i < NE; i += stride) atomicAdd(&deg[ei[i]], 1);
}

__global__ void scan_kernel(int* __restrict__ deg_cursor, int* __restrict__ row_ptr) {
    constexpr int C = 49;  // 1024*49 = 50176 >= 50000
    __shared__ int part[1024];
    const int t = threadIdx.x;
    const int base = t * C;
    int local[C];
    int s = 0;
#pragma unroll
    for (int i = 0; i < C; ++i) {
        int v = (base + i < NN) ? deg_cursor[base + i] : 0;
        local[i] = v;
        s += v;
    }
    part[t] = s;
    __syncthreads();
    for (int d = 1; d < 1024; d <<= 1) {
        int v = (t >= d) ? part[t - d] : 0;
        __syncthreads();
        part[t] += v;
        __syncthreads();
    }
    int run = part[t] - s;
#pragma unroll
    for (int i = 0; i < C; ++i) {
        const int idx = base + i;
        if (idx < NN) {
            row_ptr[idx] = run;
            deg_cursor[idx] = run;
            run += local[i];
        }
    }
    if (t == 1023) row_ptr[NN] = part[1023];
}

__global__ void scatter_kernel(const int* __restrict__ ei, int* __restrict__ cursor,
                               int* __restrict__ sorted_row, int* __restrict__ sorted_col) {
    int i = blockIdx.x * blockDim.x + threadIdx.x;
    const int stride = gridDim.x * blockDim.x;
    for (; i < NE; i += stride) {
        const int r = ei[i];
        const int c = ei[NE + i];
        const int p = atomicAdd(&cursor[r], 1);
        sorted_col[p] = c;
        sorted_row[p] = r;
    }
}

// ---------------- node precompute: a1r = h@We1[0:64]+be1, a1c = h@We1[64:128] ----------------

__global__ __launch_bounds__(256, 3) void node_pre_kernel(
    const float* __restrict__ h, const float* __restrict__ We1,
    const float* __restrict__ be1,
    unsigned short* __restrict__ a1r, unsigned short* __restrict__ a1c)
{
    __shared__ __align__(16) unsigned short sH[4][64][72];
    const int tid = threadIdx.x;
    const int lane = tid & 63, w = tid >> 6;
    const int t = blockIdx.x * 4 + w;
    const int li = lane & 15, lg = lane >> 4;

    float be1v[4];
#pragma unroll
    for (int ni = 0; ni < 4; ++ni) be1v[ni] = be1[ni * 16 + li];

#pragma unroll 4
    for (int e = 0; e < 64; ++e) {
        const int n = t * 64 + e;
        sH[w][e][lane] = (n < NN) ? f2b(h[(size_t)n * 64 + lane]) : (unsigned short)0;
    }
    __syncthreads();

#pragma unroll
    for (int half = 0; half < 2; ++half) {
        const float* W = We1 + half * 64 * 64;
        unsigned short* out = half ? a1c : a1r;
        f32x4 acc[4][4];
#pragma unroll
        for (int mi = 0; mi < 4; ++mi)
#pragma unroll
            for (int ni = 0; ni < 4; ++ni) acc[mi][ni] = (f32x4)(0.0f);
#pragma unroll
        for (int ks = 0; ks < 2; ++ks) {
            bf16x8 bfr[4], afr[4];
#pragma unroll
            for (int ni = 0; ni < 4; ++ni) bfr[ni] = load_bfrag(W, ks * 32, ni * 16, li, lg);
#pragma unroll
            for (int mi = 0; mi < 4; ++mi)
                afr[mi] = *(const bf16x8*)&sH[w][mi * 16 + li][ks * 32 + (lg << 3)];
#pragma unroll
            for (int ni = 0; ni < 4; ++ni)
#pragma unroll
                for (int mi = 0; mi < 4; ++mi)
                    acc[mi][ni] = MFMA16(afr[mi], bfr[ni], acc[mi][ni]);
        }
#pragma unroll
        for (int mi = 0; mi < 4; ++mi)
#pragma unroll
            for (int ni = 0; ni < 4; ++ni)
#pragma unroll
                for (int reg = 0; reg < 4; ++reg) {
                    const int n = t * 64 + mi * 16 + lg * 4 + reg;
                    if (n < NN) {
                        const float bias = half ? 0.0f : be1v[ni];
                        out[(size_t)n * 64 + ni * 16 + li] = f2b(acc[mi][ni][reg] + bias);
                    }
                }
    }
}

// ---------------- edge kernel: 64-edge MFMA tiles ----------------

__global__ __launch_bounds__(256, 3) void egnn_edge_kernel(
    const float* __restrict__ pos,
    const int* __restrict__ srow_g, const int* __restrict__ scol_g,
    const unsigned short* __restrict__ a1r, const unsigned short* __restrict__ a1c,
    const float* __restrict__ We1,  // only row 128 (dist weights) used
    const float* __restrict__ We2, const float* __restrict__ be2,
    const float* __restrict__ Wc1, const float* __restrict__ bc1,
    const float* __restrict__ Wc2, const float* __restrict__ bc2,
    float* __restrict__ msg_agg, float* __restrict__ pos_out)
{
    __shared__ __align__(16) unsigned short sA[4][64][72];   // m-buf, reused as msg-buf
    __shared__ int srow[4][64];
    __shared__ int scol[4][64];
    __shared__ float sdsq[4][64];
    __shared__ float scw[4][64];
    __shared__ __align__(16) unsigned short sWc1[8][64][8];  // swizzled Wc1 B-frags

    const int tid = threadIdx.x;
    // build swizzled Wc1 frags (block-shared)
    for (int idx = tid; idx < 8 * 64; idx += 256) {
        const int f = idx >> 6, ln = idx & 63;
        const int ks = f & 1, ni = f >> 1;
        const int n = ni * 16 + (ln & 15);
        const int kb = ks * 32 + ((ln >> 4) << 3);
#pragma unroll
        for (int j = 0; j < 8; ++j)
            sWc1[f][ln][j] = f2b(Wc1[(kb + j) * 64 + n]);
    }

    const int lane = tid & 63;
    const int w = tid >> 6;
    const int t = blockIdx.x * 4 + w;
    const int li = lane & 15, lg = lane >> 4;

    const float w1d = We1[128 * 64 + lane];
    float be2v[4], bc1v[4], wc2v[4];
#pragma unroll
    for (int ni = 0; ni < 4; ++ni) {
        be2v[ni] = be2[ni * 16 + li];
        bc1v[ni] = bc1[ni * 16 + li];
        wc2v[ni] = Wc2[ni * 16 + li];
    }
    const float bc2s = bc2[0];

    // We2 B-frags in registers (wave-persistent)
    bf16x8 we2f[2][4];
#pragma unroll
    for (int ks = 0; ks < 2; ++ks)
#pragma unroll
        for (int ni = 0; ni < 4; ++ni) we2f[ks][ni] = load_bfrag(We2, ks * 32, ni * 16, li, lg);

    // phase 1: per-edge scalars (lane = edge within tile)
    const int eg = t * 64 + lane;
    const int r = srow_g[eg], c = scol_g[eg];
    srow[w][lane] = r;
    scol[w][lane] = c;
    const float rx = pos[r * 3 + 0] - pos[c * 3 + 0];
    const float ry = pos[r * 3 + 1] - pos[c * 3 + 1];
    const float rz = pos[r * 3 + 2] - pos[c * 3 + 2];
    sdsq[w][lane] = rx * rx + ry * ry + rz * rz;
    __syncthreads();  // also covers sWc1 build

    // phase 2: stage m = silu(a1r[row] + a1c[col] + dsq*w1d)  (bias in a1r)
#pragma unroll 4
    for (int e = 0; e < 64; ++e) {
        const int re = srow[w][e], ce = scol[w][e];
        const float dv = sdsq[w][e];
        float m = b2f(a1r[(size_t)re * 64 + lane]) + b2f(a1c[(size_t)ce * 64 + lane]) + dv * w1d;
        sA[w][e][lane] = f2b(silu_f(m));
    }
    __syncthreads();

    // phase 3: GEMM2  msg_pre = m @ We2
    f32x4 acc[4][4];
#pragma unroll
    for (int mi = 0; mi < 4; ++mi)
#pragma unroll
        for (int ni = 0; ni < 4; ++ni) acc[mi][ni] = (f32x4)(0.0f);
#pragma unroll
    for (int ks = 0; ks < 2; ++ks) {
        bf16x8 afr[4];
#pragma unroll
        for (int mi = 0; mi < 4; ++mi)
            afr[mi] = *(const bf16x8*)&sA[w][mi * 16 + li][ks * 32 + (lg << 3)];
#pragma unroll
        for (int ni = 0; ni < 4; ++ni)
#pragma unroll
            for (int mi = 0; mi < 4; ++mi)
                acc[mi][ni] = MFMA16(afr[mi], we2f[ks][ni], acc[mi][ni]);
    }
    __syncthreads();

    // phase 4: msg = silu(msg_pre + be2) -> back into sA (C/D layout: row=lg*4+reg, col=li)
#pragma unroll
    for (int mi = 0; mi < 4; ++mi)
#pragma unroll
        for (int ni = 0; ni < 4; ++ni)
#pragma unroll
            for (int reg = 0; reg < 4; ++reg)
                sA[w][mi * 16 + lg * 4 + reg][ni * 16 + li] = f2b(silu_f(acc[mi][ni][reg] + be2v[ni]));
    __syncthreads();

    // phase 5: msg aggregation sweep (rows sorted -> run tracking, wave-uniform branch)
    {
        float macc = 0.0f;
        int pr = srow[w][0];
#pragma unroll 8
        for (int e = 0; e < 64; ++e) {
            const int re = srow[w][e];
            if (re != pr) {
                atomicAdd(&msg_agg[(size_t)pr * 64 + lane], macc);
                macc = 0.0f;
                pr = re;
            }
            macc += b2f(sA[w][e][lane]);
        }
        atomicAdd(&msg_agg[(size_t)pr * 64 + lane], macc);
    }

    // phase 6: GEMM3  t = msg @ Wc1, then cw = silu(t+bc1)@Wc2 + bc2
    f32x4 a3[4][4];
#pragma unroll
    for (int mi = 0; mi < 4; ++mi)
#pragma unroll
        for (int ni = 0; ni < 4; ++ni) a3[mi][ni] = (f32x4)(0.0f);
#pragma unroll
    for (int ks = 0; ks < 2; ++ks) {
        bf16x8 afr[4];
#pragma unroll
        for (int mi = 0; mi < 4; ++mi)
            afr[mi] = *(const bf16x8*)&sA[w][mi * 16 + li][ks * 32 + (lg << 3)];
#pragma unroll
        for (int ni = 0; ni < 4; ++ni)
#pragma unroll
            for (int mi = 0; mi < 4; ++mi)
                a3[mi][ni] = MFMA16(afr[mi], *(const bf16x8*)&sWc1[ni * 2 + ks][lane][0], a3[mi][ni]);
    }

    // epilogue: per-lane partial dots over its 4 channels, reduce over 16 lanes
    float sv[16];
#pragma unroll
    for (int mi = 0; mi < 4; ++mi)
#pragma unroll
        for (int reg = 0; reg < 4; ++reg) {
            float s = 0.0f;
#pragma unroll
            for (int ni = 0; ni < 4; ++ni)
                s += silu_f(a3[mi][ni][reg] + bc1v[ni]) * wc2v[ni];
            sv[mi * 4 + reg] = s;
        }
#pragma unroll
    for (int m = 1; m < 16; m <<= 1)
#pragma unroll
        for (int i = 0; i < 16; ++i) sv[i] += __shfl_xor(sv[i], m, 64);
    // lane (lg, li) writes edge (li>>2)*16 + lg*4 + (li&3) with value sv[li]
    float v = sv[0];
#pragma unroll
    for (int i2 = 1; i2 < 16; ++i2) v = (li == i2) ? sv[i2] : v;
    scw[w][(li >> 2) * 16 + lg * 4 + (li & 3)] = v + bc2s;
    __syncthreads();

    // phase 7: coord atomics (lane = edge; rx/ry/rz still live)
    const float cw = scw[w][lane];
    atomicAdd(&pos_out[r * 3 + 0], rx * cw);
    atomicAdd(&pos_out[r * 3 + 1], ry * cw);
    atomicAdd(&pos_out[r * 3 + 2], rz * cw);
}

// ---------------- node MLP: h_out = silu([h|msg]@Wn1+bn1)@Wn2+bn2 ----------------

__global__ __launch_bounds__(256, 2) void node_kernel(
    const float* __restrict__ h, const float* __restrict__ msg_agg,
    const float* __restrict__ Wn1, const float* __restrict__ bn1,
    const float* __restrict__ Wn2, const float* __restrict__ bn2,
    float* __restrict__ h_out)  // same region as msg_agg (tile-in-place safe)
{
    __shared__ __align__(16) unsigned short sA[4][64][136];  // K=128 staging
    const int tid = threadIdx.x;
    const int lane = tid & 63, w = tid >> 6;
    const int t = blockIdx.x * 4 + w;
    const int li = lane & 15, lg = lane >> 4;

    float bn1v[4], bn2v[4];
#pragma unroll
    for (int ni = 0; ni < 4; ++ni) {
        bn1v[ni] = bn1[ni * 16 + li];
        bn2v[ni] = bn2[ni * 16 + li];
    }

#pragma unroll 4
    for (int e = 0; e < 64; ++e) {
        const int n = t * 64 + e;
        float hv = 0.0f, mv = 0.0f;
        if (n < NN) {
            hv = h[(size_t)n * 64 + lane];
            mv = msg_agg[(size_t)n * 64 + lane];
        }
        sA[w][e][lane] = f2b(hv);
        sA[w][e][64 + lane] = f2b(mv);
    }
    __syncthreads();

    // GEMM1: K=128
    f32x4 acc[4][4];
#pragma unroll
    for (int mi = 0; mi < 4; ++mi)
#pragma unroll
        for (int ni = 0; ni < 4; ++ni) acc[mi][ni] = (f32x4)(0.0f);
#pragma unroll
    for (int ks = 0; ks < 4; ++ks) {
        bf16x8 bfr[4], afr[4];
#pragma unroll
        for (int ni = 0; ni < 4; ++ni) bfr[ni] = load_bfrag(Wn1, ks * 32, ni * 16, li, lg);
#pragma unroll
        for (int mi = 0; mi < 4; ++mi)
            afr[mi] = *(const bf16x8*)&sA[w][mi * 16 + li][ks * 32 + (lg << 3)];
#pragma unroll
        for (int ni = 0; ni < 4; ++ni)
#pragma unroll
            for (int mi = 0; mi < 4; ++mi)
                acc[mi][ni] = MFMA16(afr[mi], bfr[ni], acc[mi][ni]);
    }
    __syncthreads();
    // silu + bn1 -> sA cols 0..63
#pragma unroll
    for (int mi = 0; mi < 4; ++mi)
#pragma unroll
        for (int ni = 0; ni < 4; ++ni)
#pragma unroll
            for (int reg = 0; reg < 4; ++reg)
                sA[w][mi * 16 + lg * 4 + reg][ni * 16 + li] = f2b(silu_f(acc[mi][ni][reg] + bn1v[ni]));
    __syncthreads();

    // GEMM2: K=64
    f32x4 a2[4][4];
#pragma unroll
    for (int mi = 0; mi < 4; ++mi)
#pragma unroll
        for (int ni = 0; ni < 4; ++ni) a2[mi][ni] = (f32x4)(0.0f);
#pragma unroll
    for (int ks = 0; ks < 2; ++ks) {
        bf16x8 bfr[4], afr[4];
#pragma unroll
        for (int ni = 0; ni < 4; ++ni) bfr[ni] = load_bfrag(Wn2, ks * 32, ni * 16, li, lg);
#pragma unroll
        for (int mi = 0; mi < 4; ++mi)
            afr[mi] = *(const bf16x8*)&sA[w][mi * 16 + li][ks * 32 + (lg << 3)];
#pragma unroll
        for (int ni = 0; ni < 4; ++ni)
#pragma unroll
            for (int mi = 0; mi < 4; ++mi)
                a2[mi][ni] = MFMA16(afr[mi], bfr[ni], a2[mi][ni]);
    }
#pragma unroll
    for (int mi = 0; mi < 4; ++mi)
#pragma unroll
        for (int ni = 0; ni < 4; ++ni)
#pragma unroll
            for (int reg = 0; reg < 4; ++reg) {
                const int n = t * 64 + mi * 16 + lg * 4 + reg;
                if (n < NN) h_out[(size_t)n * 64 + ni * 16 + li] = a2[mi][ni][reg] + bn2v[ni];
            }
}

// ---------------- launch ----------------

extern "C" void kernel_launch(void* const* d_in, const int* in_sizes, int n_in,
                              void* d_out, int out_size, void* d_ws, size_t ws_size,
                              hipStream_t stream) {
    const float* h   = (const float*)d_in[0];
    const float* pos = (const float*)d_in[1];
    const int*   ei  = (const int*)d_in[2];
    const float* We1 = (const float*)d_in[3];
    const float* be1 = (const float*)d_in[4];
    const float* We2 = (const float*)d_in[5];
    const float* be2 = (const float*)d_in[6];
    const float* Wc1 = (const float*)d_in[7];
    const float* bc1 = (const float*)d_in[8];
    const float* Wc2 = (const float*)d_in[9];
    const float* bc2 = (const float*)d_in[10];
    const float* Wn1 = (const float*)d_in[11];
    const float* bn1 = (const float*)d_in[12];
    const float* Wn2 = (const float*)d_in[13];
    const float* bn2 = (const float*)d_in[14];

    // workspace (~19.6 MB)
    unsigned short* a1r = (unsigned short*)d_ws;             // [N,64] bf16
    unsigned short* a1c = a1r + (size_t)NN * 64;             // [N,64] bf16
    int* sorted_col = (int*)(a1c + (size_t)NN * 64);         // [E]
    int* sorted_row = sorted_col + NE;                       // [E]
    int* row_ptr    = sorted_row + NE;                       // [N+1]
    int* cursor     = row_ptr + NN + 1;                      // [N]

    float* msg_agg = (float*)d_out;                          // reused as h_out
    float* pos_out = msg_agg + (size_t)NN * 64;

    // counting sort by row
    hipMemsetAsync(cursor, 0, (size_t)NN * sizeof(int), stream);
    hist_kernel<<<1024, 256, 0, stream>>>(ei, cursor);
    scan_kernel<<<1, 1024, 0, stream>>>(cursor, row_ptr);
    scatter_kernel<<<1024, 256, 0, stream>>>(ei, cursor, sorted_row, sorted_col);

    // per-node a1 tables
    node_pre_kernel<<<196, 256, 0, stream>>>(h, We1, be1, a1r, a1c);

    // init accumulators: msg_agg = 0, pos_out = pos
    hipMemsetAsync(msg_agg, 0, (size_t)NN * 64 * sizeof(float), stream);
    hipMemcpyAsync(pos_out, pos, (size_t)NN * 3 * sizeof(float),
                   hipMemcpyDeviceToDevice, stream);

    egnn_edge_kernel<<<3125, 256, 0, stream>>>(pos, sorted_row, sorted_col, a1r, a1c,
                                               We1, We2, be2, Wc1, bc1, Wc2, bc2,
                                               msg_agg, pos_out);
    node_kernel<<<196, 256, 0, stream>>>(h, msg_agg, Wn1, bn1, Wn2, bn2, msg_agg);
}

// Round 4
// 508.270 us; speedup vs baseline: 12.7895x; 1.0746x over previous
//
#include <hip/hip_runtime.h>

// EGNN conv: N=50000, E=800000, C=64.
// Round 4: (a) edge tile = one block (4 waves x 16 edges, wave-private sA rows,
// 2 barriers only), LDS 12KB -> high occupancy + 16-deep gather batches;
// (b) global bf16 B-frag table prebuilt once (no per-block weight rebuild);
// (c) silu via v_rcp, f2b via add+shift; (d) fused prep kernel (node_pre ||
// frag-build || hist || msg_agg zero || pos_out init), int4 scan, int2 scatter.
// Round-3 evidence: edge 230us at Occ 28%/VALU 45% = gather-latency x occupancy
// bound; non-edge ~316us across 9 serialized stream ops.

#define NN 50000
#define NE 800000
#define NTILE 782           // ceil(NN/64)
#define ETILE 12500         // NE/64
#define SCAN_PAD 53248      // 1024*52

typedef __attribute__((ext_vector_type(8))) short bf16x8;
typedef __attribute__((ext_vector_type(4))) float f32x4;

#define MFMA16(a, b, c) __builtin_amdgcn_mfma_f32_16x16x32_bf16(a, b, c, 0, 0, 0)

__device__ __forceinline__ unsigned short f2b(float x) {
    union { float f; unsigned u; } v; v.f = x;
    return (unsigned short)((v.u + 0x8000u) >> 16);  // round-half-up (<=0.5 ulp)
}
__device__ __forceinline__ float b2f(unsigned short b) {
    union { unsigned u; float f; } v; v.u = ((unsigned)b) << 16; return v.f;
}
__device__ __forceinline__ float silu_f(float x) {
    // x * rcp(1+exp(-x)) : v_exp + v_rcp, no IEEE divide sequence
    return x * __builtin_amdgcn_rcpf(1.0f + __expf(-x));
}

// ---------------- K1: fused prep (block-split roles) ----------------
// blocks [0,196): node_pre (a1r/a1c via MFMA), [196,206): frag table build,
// [206,1230): hist, [1230,1430): msg_agg zero, [1430,1438): pos_out = pos.

#define B_NPRE 196
#define B_FRAG 10
#define B_HIST 1024
#define B_ZERO 200
#define B_COPY 8
#define K1_GRID (B_NPRE + B_FRAG + B_HIST + B_ZERO + B_COPY)

__global__ __launch_bounds__(256, 4) void prep_kernel(
    const float* __restrict__ h, const float* __restrict__ pos,
    const int* __restrict__ ei,
    const float* __restrict__ We1, const float* __restrict__ be1,
    const float* __restrict__ We2, const float* __restrict__ Wc1,
    const float* __restrict__ Wn1, const float* __restrict__ Wn2,
    unsigned short* __restrict__ a1r, unsigned short* __restrict__ a1c,
    unsigned short* __restrict__ wfrag, int* __restrict__ cursor,
    float* __restrict__ msg_agg, float* __restrict__ pos_out)
{
    __shared__ __align__(16) unsigned short sH[4][64][72];
    const int b = blockIdx.x;
    const int tid = threadIdx.x;
    const int lane = tid & 63, w = tid >> 6;
    const int li = lane & 15, lg = lane >> 4;

    if (b < B_NPRE) {
        // ---- node_pre: a1r = h@We1[0:64]+be1, a1c = h@We1[64:128] (bf16) ----
        const int t = b * 4 + w;
        float be1v[4];
#pragma unroll
        for (int ni = 0; ni < 4; ++ni) be1v[ni] = be1[ni * 16 + li];
#pragma unroll 4
        for (int e = 0; e < 64; ++e) {
            const int n = t * 64 + e;
            sH[w][e][lane] = (n < NN) ? f2b(h[(size_t)n * 64 + lane]) : (unsigned short)0;
        }
        __syncthreads();
#pragma unroll
        for (int half = 0; half < 2; ++half) {
            const float* W = We1 + half * 64 * 64;
            unsigned short* out = half ? a1c : a1r;
            f32x4 acc[4][4];
#pragma unroll
            for (int mi = 0; mi < 4; ++mi)
#pragma unroll
                for (int ni = 0; ni < 4; ++ni) acc[mi][ni] = (f32x4)(0.0f);
#pragma unroll
            for (int ks = 0; ks < 2; ++ks) {
                bf16x8 bfr[4], afr[4];
#pragma unroll
                for (int ni = 0; ni < 4; ++ni) {
                    const int n = ni * 16 + li;
                    const int kb = ks * 32 + (lg << 3);
                    bf16x8 v;
#pragma unroll
                    for (int j = 0; j < 8; ++j) v[j] = (short)f2b(W[(kb + j) * 64 + n]);
                    bfr[ni] = v;
                }
#pragma unroll
                for (int mi = 0; mi < 4; ++mi)
                    afr[mi] = *(const bf16x8*)&sH[w][mi * 16 + li][ks * 32 + (lg << 3)];
#pragma unroll
                for (int ni = 0; ni < 4; ++ni)
#pragma unroll
                    for (int mi = 0; mi < 4; ++mi)
                        acc[mi][ni] = MFMA16(afr[mi], bfr[ni], acc[mi][ni]);
            }
#pragma unroll
            for (int mi = 0; mi < 4; ++mi)
#pragma unroll
                for (int ni = 0; ni < 4; ++ni)
#pragma unroll
                    for (int reg = 0; reg < 4; ++reg) {
                        const int n = t * 64 + mi * 16 + lg * 4 + reg;
                        if (n < NN) {
                            const float bias = half ? 0.0f : be1v[ni];
                            out[(size_t)n * 64 + ni * 16 + li] = f2b(acc[mi][ni][reg] + bias);
                        }
                    }
        }
    } else if (b < B_NPRE + B_FRAG) {
        // ---- B-frag table: We2 f=0..7, Wc1 8..15, Wn1 16..31, Wn2 32..39 ----
        const int f = (b - B_NPRE) * 4 + w;
        const float* W;
        int g;
        if (f < 8)       { W = We2; g = f; }
        else if (f < 16) { W = Wc1; g = f - 8; }
        else if (f < 32) { W = Wn1; g = f - 16; }
        else             { W = Wn2; g = f - 32; }
        const int ks = g >> 2, ni = g & 3;
        const int n = ni * 16 + li;
        const int kb = ks * 32 + (lg << 3);
        bf16x8 v;
#pragma unroll
        for (int j = 0; j < 8; ++j) v[j] = (short)f2b(W[(kb + j) * 64 + n]);
        *(bf16x8*)(wfrag + (size_t)f * 512 + lane * 8) = v;
    } else if (b < B_NPRE + B_FRAG + B_HIST) {
        // ---- hist: deg[row]++ ----
        int i = (b - B_NPRE - B_FRAG) * 256 + tid;
        for (; i < NE; i += B_HIST * 256) atomicAdd(&cursor[ei[i]], 1);
    } else if (b < B_NPRE + B_FRAG + B_HIST + B_ZERO) {
        // ---- msg_agg = 0 (float4) ----
        float4* dst = (float4*)msg_agg;
        int i = (b - B_NPRE - B_FRAG - B_HIST) * 256 + tid;
        for (; i < NN * 16; i += B_ZERO * 256) dst[i] = make_float4(0.f, 0.f, 0.f, 0.f);
    } else {
        // ---- pos_out = pos (float4, 150000 floats = 37500 float4) ----
        const float4* src = (const float4*)pos;
        float4* dst = (float4*)pos_out;
        int i = (b - B_NPRE - B_FRAG - B_HIST - B_ZERO) * 256 + tid;
        for (; i < 37500; i += B_COPY * 256) dst[i] = src[i];
    }
}

// ---------------- K2: single-block scan (int4 loads), in-place ----------------

__global__ void scan_kernel(int* __restrict__ cur) {
    __shared__ int part[1024];
    const int t = threadIdx.x;
    int4 v[13];
    const int4* src = (const int4*)cur + t * 13;
#pragma unroll
    for (int i = 0; i < 13; ++i) v[i] = src[i];
    int local[52];
#pragma unroll
    for (int i = 0; i < 13; ++i) {
        local[4 * i + 0] = v[i].x; local[4 * i + 1] = v[i].y;
        local[4 * i + 2] = v[i].z; local[4 * i + 3] = v[i].w;
    }
    int s = 0;
#pragma unroll
    for (int i = 0; i < 52; ++i) s += local[i];
    part[t] = s;
    __syncthreads();
    for (int d = 1; d < 1024; d <<= 1) {
        int pv = (t >= d) ? part[t - d] : 0;
        __syncthreads();
        part[t] += pv;
        __syncthreads();
    }
    int run = part[t] - s;  // exclusive prefix of this chunk
    const int base = t * 52;
#pragma unroll
    for (int i = 0; i < 52; ++i) {
        const int idx = base + i;
        if (idx < NN) cur[idx] = run;
        run += local[i];
    }
}

// ---------------- K3: scatter (packed int2) ----------------

__global__ void scatter_kernel(const int* __restrict__ ei, int* __restrict__ cursor,
                               int2* __restrict__ sorted_rc) {
    int i = blockIdx.x * blockDim.x + threadIdx.x;
    const int stride = gridDim.x * blockDim.x;
    for (; i < NE; i += stride) {
        const int r = ei[i];
        const int c = ei[NE + i];
        const int p = atomicAdd(&cursor[r], 1);
        sorted_rc[p] = make_int2(r, c);
    }
}

// ---------------- K4: edge kernel, one 64-edge tile per block ----------------

__global__ __launch_bounds__(256, 6) void egnn_edge_kernel(
    const float* __restrict__ pos, const int2* __restrict__ sorted_rc,
    const unsigned short* __restrict__ a1r, const unsigned short* __restrict__ a1c,
    const float* __restrict__ We1,  // row 128 = dist weights
    const unsigned short* __restrict__ wfrag,
    const float* __restrict__ be2, const float* __restrict__ bc1,
    const float* __restrict__ Wc2, const float* __restrict__ bc2,
    float* __restrict__ msg_agg, float* __restrict__ pos_out)
{
    __shared__ __align__(16) unsigned short sA[64][80];  // [edge][chan], stride 80 = 16B-mult
    __shared__ int sre[64];
    __shared__ int sce[64];
    __shared__ float sdsq[64];
    __shared__ float scw[64];

    const int tid = threadIdx.x;
    const int lane = tid & 63, w = tid >> 6;
    const int li = lane & 15, lg = lane >> 4;
    const int tile = blockIdx.x;

    // phase 0: tid<64 loads its edge's endpoints + relpos (held in regs for phase 7)
    float rx = 0.f, ry = 0.f, rz = 0.f;
    int r_e = 0;
    if (tid < 64) {
        const int2 rc = sorted_rc[tile * 64 + tid];
        r_e = rc.x;
        rx = pos[3 * rc.x + 0] - pos[3 * rc.y + 0];
        ry = pos[3 * rc.x + 1] - pos[3 * rc.y + 1];
        rz = pos[3 * rc.x + 2] - pos[3 * rc.y + 2];
        sre[tid] = rc.x;
        sce[tid] = rc.y;
        sdsq[tid] = rx * rx + ry * ry + rz * rz;
    }

    const float w1d = We1[128 * 64 + lane];
    float be2v[4], bc1v[4], wc2v[4];
#pragma unroll
    for (int ni = 0; ni < 4; ++ni) {
        be2v[ni] = be2[ni * 16 + li];
        bc1v[ni] = bc1[ni * 16 + li];
        wc2v[ni] = Wc2[ni * 16 + li];
    }
    const float bc2s = bc2[0];
    __syncthreads();

    // phase 2: wave w stages m for its 16 edges [e0, e0+16) — sA rows are
    // wave-private from here on (no further barriers until scw).
    const int e0 = w * 16;
#pragma unroll
    for (int hh = 0; hh < 2; ++hh) {
        int re8[8], ce8[8];
        float dv8[8];
#pragma unroll
        for (int j = 0; j < 8; ++j) {
            const int e = e0 + hh * 8 + j;
            re8[j] = sre[e]; ce8[j] = sce[e]; dv8[j] = sdsq[e];
        }
        unsigned short ar8[8], ac8[8];
#pragma unroll
        for (int j = 0; j < 8; ++j) {
            ar8[j] = a1r[(size_t)re8[j] * 64 + lane];
            ac8[j] = a1c[(size_t)ce8[j] * 64 + lane];
        }
#pragma unroll
        for (int j = 0; j < 8; ++j) {
            const float m = b2f(ar8[j]) + b2f(ac8[j]) + dv8[j] * w1d;
            sA[e0 + hh * 8 + j][lane] = f2b(silu_f(m));
        }
    }

    // phase 3: GEMM2 (msg_pre = m @ We2), 16 rows per wave
    f32x4 acc[4];
#pragma unroll
    for (int ni = 0; ni < 4; ++ni) acc[ni] = (f32x4)(0.0f);
#pragma unroll
    for (int ks = 0; ks < 2; ++ks) {
        const bf16x8 af = *(const bf16x8*)&sA[e0 + li][ks * 32 + (lg << 3)];
#pragma unroll
        for (int ni = 0; ni < 4; ++ni) {
            const bf16x8 bf = *(const bf16x8*)(wfrag + (size_t)(ks * 4 + ni) * 512 + lane * 8);
            acc[ni] = MFMA16(af, bf, acc[ni]);
        }
    }

    // phase 4: msg = silu(msg_pre + be2) -> sA [edge][chan] (own rows)
#pragma unroll
    for (int ni = 0; ni < 4; ++ni)
#pragma unroll
        for (int reg = 0; reg < 4; ++reg)
            sA[e0 + lg * 4 + reg][ni * 16 + li] = f2b(silu_f(acc[ni][reg] + be2v[ni]));

    // phase 5: quarter sweep (rows non-decreasing; wave-uniform branch)
    {
        float macc = 0.0f;
        int pr = sre[e0];
#pragma unroll
        for (int j = 0; j < 16; ++j) {
            const int re = sre[e0 + j];
            if (re != pr) {
                atomicAdd(&msg_agg[(size_t)pr * 64 + lane], macc);
                macc = 0.0f;
                pr = re;
            }
            macc += b2f(sA[e0 + j][lane]);
        }
        atomicAdd(&msg_agg[(size_t)pr * 64 + lane], macc);
    }

    // phase 6: GEMM3 (t = msg @ Wc1)
    f32x4 a3[4];
#pragma unroll
    for (int ni = 0; ni < 4; ++ni) a3[ni] = (f32x4)(0.0f);
#pragma unroll
    for (int ks = 0; ks < 2; ++ks) {
        const bf16x8 af = *(const bf16x8*)&sA[e0 + li][ks * 32 + (lg << 3)];
#pragma unroll
        for (int ni = 0; ni < 4; ++ni) {
            const bf16x8 bf = *(const bf16x8*)(wfrag + (size_t)(8 + ks * 4 + ni) * 512 + lane * 8);
            a3[ni] = MFMA16(af, bf, a3[ni]);
        }
    }

    // epilogue: cw[edge] = sum_c silu(t+bc1)[c] * Wc2[c]; reduce over li lanes
    float sv[4];
#pragma unroll
    for (int reg = 0; reg < 4; ++reg) {
        float s = 0.0f;
#pragma unroll
        for (int ni = 0; ni < 4; ++ni)
            s += silu_f(a3[ni][reg] + bc1v[ni]) * wc2v[ni];
        sv[reg] = s;
    }
#pragma unroll
    for (int m = 1; m < 16; m <<= 1)
#pragma unroll
        for (int reg = 0; reg < 4; ++reg) sv[reg] += __shfl_xor(sv[reg], m, 64);
    if (li == 0) {
        float4 cv = make_float4(sv[0] + bc2s, sv[1] + bc2s, sv[2] + bc2s, sv[3] + bc2s);
        *(float4*)&scw[e0 + lg * 4] = cv;
    }
    __syncthreads();

    // phase 7: coord atomics (tid<64 holds rx/ry/rz/r_e)
    if (tid < 64) {
        const float cw = scw[tid];
        atomicAdd(&pos_out[r_e * 3 + 0], rx * cw);
        atomicAdd(&pos_out[r_e * 3 + 1], ry * cw);
        atomicAdd(&pos_out[r_e * 3 + 2], rz * cw);
    }
}

// ---------------- K5: node MLP ----------------

__global__ __launch_bounds__(256, 2) void node_kernel(
    const float* __restrict__ h, const float* __restrict__ msg_agg,
    const unsigned short* __restrict__ wfrag,
    const float* __restrict__ bn1, const float* __restrict__ bn2,
    float* __restrict__ h_out)
{
    __shared__ __align__(16) unsigned short sA[4][64][136];
    const int tid = threadIdx.x;
    const int lane = tid & 63, w = tid >> 6;
    const int t = blockIdx.x * 4 + w;
    const int li = lane & 15, lg = lane >> 4;

    float bn1v[4], bn2v[4];
#pragma unroll
    for (int ni = 0; ni < 4; ++ni) {
        bn1v[ni] = bn1[ni * 16 + li];
        bn2v[ni] = bn2[ni * 16 + li];
    }

#pragma unroll 4
    for (int e = 0; e < 64; ++e) {
        const int n = t * 64 + e;
        float hv = 0.0f, mv = 0.0f;
        if (n < NN) {
            hv = h[(size_t)n * 64 + lane];
            mv = msg_agg[(size_t)n * 64 + lane];
        }
        sA[w][e][lane] = f2b(hv);
        sA[w][e][64 + lane] = f2b(mv);
    }

    // GEMM1: K=128 (sA rows are wave-private; lgkm ordering suffices)
    f32x4 acc[4][4];
#pragma unroll
    for (int mi = 0; mi < 4; ++mi)
#pragma unroll
        for (int ni = 0; ni < 4; ++ni) acc[mi][ni] = (f32x4)(0.0f);
#pragma unroll
    for (int ks = 0; ks < 4; ++ks) {
        bf16x8 bfr[4], afr[4];
#pragma unroll
        for (int ni = 0; ni < 4; ++ni)
            bfr[ni] = *(const bf16x8*)(wfrag + (size_t)(16 + ks * 4 + ni) * 512 + lane * 8);
#pragma unroll
        for (int mi = 0; mi < 4; ++mi)
            afr[mi] = *(const bf16x8*)&sA[w][mi * 16 + li][ks * 32 + (lg << 3)];
#pragma unroll
        for (int ni = 0; ni < 4; ++ni)
#pragma unroll
            for (int mi = 0; mi < 4; ++mi)
                acc[mi][ni] = MFMA16(afr[mi], bfr[ni], acc[mi][ni]);
    }
    // silu + bn1 -> sA cols 0..63 (own rows)
#pragma unroll
    for (int mi = 0; mi < 4; ++mi)
#pragma unroll
        for (int ni = 0; ni < 4; ++ni)
#pragma unroll
            for (int reg = 0; reg < 4; ++reg)
                sA[w][mi * 16 + lg * 4 + reg][ni * 16 + li] = f2b(silu_f(acc[mi][ni][reg] + bn1v[ni]));

    // GEMM2: K=64
    f32x4 a2[4][4];
#pragma unroll
    for (int mi = 0; mi < 4; ++mi)
#pragma unroll
        for (int ni = 0; ni < 4; ++ni) a2[mi][ni] = (f32x4)(0.0f);
#pragma unroll
    for (int ks = 0; ks < 2; ++ks) {
        bf16x8 bfr[4], afr[4];
#pragma unroll
        for (int ni = 0; ni < 4; ++ni)
            bfr[ni] = *(const bf16x8*)(wfrag + (size_t)(32 + ks * 4 + ni) * 512 + lane * 8);
#pragma unroll
        for (int mi = 0; mi < 4; ++mi)
            afr[mi] = *(const bf16x8*)&sA[w][mi * 16 + li][ks * 32 + (lg << 3)];
#pragma unroll
        for (int ni = 0; ni < 4; ++ni)
#pragma unroll
            for (int mi = 0; mi < 4; ++mi)
                a2[mi][ni] = MFMA16(afr[mi], bfr[ni], a2[mi][ni]);
    }
#pragma unroll
    for (int mi = 0; mi < 4; ++mi)
#pragma unroll
        for (int ni = 0; ni < 4; ++ni)
#pragma unroll
            for (int reg = 0; reg < 4; ++reg) {
                const int n = t * 64 + mi * 16 + lg * 4 + reg;
                if (n < NN) h_out[(size_t)n * 64 + ni * 16 + li] = a2[mi][ni][reg] + bn2v[ni];
            }
}

// ---------------- launch ----------------

extern "C" void kernel_launch(void* const* d_in, const int* in_sizes, int n_in,
                              void* d_out, int out_size, void* d_ws, size_t ws_size,
                              hipStream_t stream) {
    const float* h   = (const float*)d_in[0];
    const float* pos = (const float*)d_in[1];
    const int*   ei  = (const int*)d_in[2];
    const float* We1 = (const float*)d_in[3];
    const float* be1 = (const float*)d_in[4];
    const float* We2 = (const float*)d_in[5];
    const float* be2 = (const float*)d_in[6];
    const float* Wc1 = (const float*)d_in[7];
    const float* bc1 = (const float*)d_in[8];
    const float* Wc2 = (const float*)d_in[9];
    const float* bc2 = (const float*)d_in[10];
    const float* Wn1 = (const float*)d_in[11];
    const float* bn1 = (const float*)d_in[12];
    const float* Wn2 = (const float*)d_in[13];
    const float* bn2 = (const float*)d_in[14];

    // workspace (~19.5 MB)
    unsigned short* a1r   = (unsigned short*)d_ws;            // [N*64] bf16
    unsigned short* a1c   = a1r + (size_t)NN * 64;            // [N*64] bf16
    unsigned short* wfrag = a1c + (size_t)NN * 64;            // 40 frags * 512
    int2* sorted_rc = (int2*)(wfrag + 40 * 512);              // [E]
    int*  cursor    = (int*)(sorted_rc + NE);                 // [SCAN_PAD]

    float* msg_agg = (float*)d_out;                           // reused as h_out
    float* pos_out = msg_agg + (size_t)NN * 64;

    hipMemsetAsync(cursor, 0, (size_t)SCAN_PAD * sizeof(int), stream);
    prep_kernel<<<K1_GRID, 256, 0, stream>>>(h, pos, ei, We1, be1, We2, Wc1, Wn1, Wn2,
                                             a1r, a1c, wfrag, cursor, msg_agg, pos_out);
    scan_kernel<<<1, 1024, 0, stream>>>(cursor);
    scatter_kernel<<<1024, 256, 0, stream>>>(ei, cursor, sorted_rc);
    egnn_edge_kernel<<<ETILE, 256, 0, stream>>>(pos, sorted_rc, a1r, a1c, We1, wfrag,
                                                be2, bc1, Wc2, bc2, msg_agg, pos_out);
    node_kernel<<<196, 256, 0, stream>>>(h, msg_agg, wfrag, bn1, bn2, msg_agg);
}

// Round 5
// 334.459 us; speedup vs baseline: 19.4360x; 1.5197x over previous
//
#include <hip/hip_runtime.h>

// EGNN conv: N=50000, E=800000, C=64.
// Round 5: edge kernel gathers restructured to 16B row-chunks (8 lanes/row,
// dwordx4) -> 32x fewer L2 line requests than per-lane u16 gathers; coord
// segment-sum via wave segmented scan (1 atomic/row instead of 1/edge);
// node kernel staging vectorized (float4 + ds_write_b64).
// Round-4 evidence: edge 220us flat despite 2x occupancy; VALUBusy 28%;
// WRITE_SIZE 209MB ~= 2.4M coord atomics x 64B lines; gather line-requests
// ~102M ~= L2 saturation. This round attacks L2 request count + atomic count.

#define NN 50000
#define NE 800000
#define ETILE 12500         // NE/64
#define SCAN_PAD 53248      // 1024*52

typedef __attribute__((ext_vector_type(8))) short bf16x8;
typedef __attribute__((ext_vector_type(4))) float f32x4;

#define MFMA16(a, b, c) __builtin_amdgcn_mfma_f32_16x16x32_bf16(a, b, c, 0, 0, 0)

__device__ __forceinline__ unsigned short f2b(float x) {
    union { float f; unsigned u; } v; v.f = x;
    return (unsigned short)((v.u + 0x8000u) >> 16);  // round-half-up (<=0.5 ulp)
}
__device__ __forceinline__ float b2f(unsigned short b) {
    union { unsigned u; float f; } v; v.u = ((unsigned)b) << 16; return v.f;
}
__device__ __forceinline__ float silu_f(float x) {
    return x * __builtin_amdgcn_rcpf(1.0f + __expf(-x));
}

// ---------------- K1: fused prep (block-split roles) ----------------

#define B_NPRE 196
#define B_FRAG 10
#define B_HIST 1024
#define B_ZERO 200
#define B_COPY 8
#define K1_GRID (B_NPRE + B_FRAG + B_HIST + B_ZERO + B_COPY)

__global__ __launch_bounds__(256, 4) void prep_kernel(
    const float* __restrict__ h, const float* __restrict__ pos,
    const int* __restrict__ ei,
    const float* __restrict__ We1, const float* __restrict__ be1,
    const float* __restrict__ We2, const float* __restrict__ Wc1,
    const float* __restrict__ Wn1, const float* __restrict__ Wn2,
    unsigned short* __restrict__ a1r, unsigned short* __restrict__ a1c,
    unsigned short* __restrict__ wfrag, int* __restrict__ cursor,
    float* __restrict__ msg_agg, float* __restrict__ pos_out)
{
    __shared__ __align__(16) unsigned short sH[4][64][72];
    const int b = blockIdx.x;
    const int tid = threadIdx.x;
    const int lane = tid & 63, w = tid >> 6;
    const int li = lane & 15, lg = lane >> 4;

    if (b < B_NPRE) {
        const int t = b * 4 + w;
        float be1v[4];
#pragma unroll
        for (int ni = 0; ni < 4; ++ni) be1v[ni] = be1[ni * 16 + li];
#pragma unroll 4
        for (int e = 0; e < 64; ++e) {
            const int n = t * 64 + e;
            sH[w][e][lane] = (n < NN) ? f2b(h[(size_t)n * 64 + lane]) : (unsigned short)0;
        }
        __syncthreads();
#pragma unroll
        for (int half = 0; half < 2; ++half) {
            const float* W = We1 + half * 64 * 64;
            unsigned short* out = half ? a1c : a1r;
            f32x4 acc[4][4];
#pragma unroll
            for (int mi = 0; mi < 4; ++mi)
#pragma unroll
                for (int ni = 0; ni < 4; ++ni) acc[mi][ni] = (f32x4)(0.0f);
#pragma unroll
            for (int ks = 0; ks < 2; ++ks) {
                bf16x8 bfr[4], afr[4];
#pragma unroll
                for (int ni = 0; ni < 4; ++ni) {
                    const int n = ni * 16 + li;
                    const int kb = ks * 32 + (lg << 3);
                    bf16x8 v;
#pragma unroll
                    for (int j = 0; j < 8; ++j) v[j] = (short)f2b(W[(kb + j) * 64 + n]);
                    bfr[ni] = v;
                }
#pragma unroll
                for (int mi = 0; mi < 4; ++mi)
                    afr[mi] = *(const bf16x8*)&sH[w][mi * 16 + li][ks * 32 + (lg << 3)];
#pragma unroll
                for (int ni = 0; ni < 4; ++ni)
#pragma unroll
                    for (int mi = 0; mi < 4; ++mi)
                        acc[mi][ni] = MFMA16(afr[mi], bfr[ni], acc[mi][ni]);
            }
#pragma unroll
            for (int mi = 0; mi < 4; ++mi)
#pragma unroll
                for (int ni = 0; ni < 4; ++ni)
#pragma unroll
                    for (int reg = 0; reg < 4; ++reg) {
                        const int n = t * 64 + mi * 16 + lg * 4 + reg;
                        if (n < NN) {
                            const float bias = half ? 0.0f : be1v[ni];
                            out[(size_t)n * 64 + ni * 16 + li] = f2b(acc[mi][ni][reg] + bias);
                        }
                    }
        }
    } else if (b < B_NPRE + B_FRAG) {
        const int f = (b - B_NPRE) * 4 + w;
        const float* W;
        int g;
        if (f < 8)       { W = We2; g = f; }
        else if (f < 16) { W = Wc1; g = f - 8; }
        else if (f < 32) { W = Wn1; g = f - 16; }
        else             { W = Wn2; g = f - 32; }
        const int ks = g >> 2, ni = g & 3;
        const int n = ni * 16 + li;
        const int kb = ks * 32 + (lg << 3);
        bf16x8 v;
#pragma unroll
        for (int j = 0; j < 8; ++j) v[j] = (short)f2b(W[(kb + j) * 64 + n]);
        *(bf16x8*)(wfrag + (size_t)f * 512 + lane * 8) = v;
    } else if (b < B_NPRE + B_FRAG + B_HIST) {
        int i = (b - B_NPRE - B_FRAG) * 256 + tid;
        for (; i < NE; i += B_HIST * 256) atomicAdd(&cursor[ei[i]], 1);
    } else if (b < B_NPRE + B_FRAG + B_HIST + B_ZERO) {
        float4* dst = (float4*)msg_agg;
        int i = (b - B_NPRE - B_FRAG - B_HIST) * 256 + tid;
        for (; i < NN * 16; i += B_ZERO * 256) dst[i] = make_float4(0.f, 0.f, 0.f, 0.f);
    } else {
        const float4* src = (const float4*)pos;
        float4* dst = (float4*)pos_out;
        int i = (b - B_NPRE - B_FRAG - B_HIST - B_ZERO) * 256 + tid;
        for (; i < 37500; i += B_COPY * 256) dst[i] = src[i];
    }
}

// ---------------- K2: single-block scan (int4 loads), in-place ----------------

__global__ void scan_kernel(int* __restrict__ cur) {
    __shared__ int part[1024];
    const int t = threadIdx.x;
    int4 v[13];
    const int4* src = (const int4*)cur + t * 13;
#pragma unroll
    for (int i = 0; i < 13; ++i) v[i] = src[i];
    int local[52];
#pragma unroll
    for (int i = 0; i < 13; ++i) {
        local[4 * i + 0] = v[i].x; local[4 * i + 1] = v[i].y;
        local[4 * i + 2] = v[i].z; local[4 * i + 3] = v[i].w;
    }
    int s = 0;
#pragma unroll
    for (int i = 0; i < 52; ++i) s += local[i];
    part[t] = s;
    __syncthreads();
    for (int d = 1; d < 1024; d <<= 1) {
        int pv = (t >= d) ? part[t - d] : 0;
        __syncthreads();
        part[t] += pv;
        __syncthreads();
    }
    int run = part[t] - s;
    const int base = t * 52;
#pragma unroll
    for (int i = 0; i < 52; ++i) {
        const int idx = base + i;
        if (idx < NN) cur[idx] = run;
        run += local[i];
    }
}

// ---------------- K3: scatter (packed int2) ----------------

__global__ void scatter_kernel(const int* __restrict__ ei, int* __restrict__ cursor,
                               int2* __restrict__ sorted_rc) {
    int i = blockIdx.x * blockDim.x + threadIdx.x;
    const int stride = gridDim.x * blockDim.x;
    for (; i < NE; i += stride) {
        const int r = ei[i];
        const int c = ei[NE + i];
        const int p = atomicAdd(&cursor[r], 1);
        sorted_rc[p] = make_int2(r, c);
    }
}

// ---------------- K4: edge kernel, one 64-edge tile per block ----------------

__global__ __launch_bounds__(256, 6) void egnn_edge_kernel(
    const float* __restrict__ pos, const int2* __restrict__ sorted_rc,
    const unsigned short* __restrict__ a1r, const unsigned short* __restrict__ a1c,
    const float* __restrict__ We1,  // row 128 = dist weights
    const unsigned short* __restrict__ wfrag,
    const float* __restrict__ be2, const float* __restrict__ bc1,
    const float* __restrict__ Wc2, const float* __restrict__ bc2,
    float* __restrict__ msg_agg, float* __restrict__ pos_out)
{
    __shared__ __align__(16) unsigned short sA[64][80];  // [edge][chan]
    __shared__ int sre[64];
    __shared__ int sce[64];
    __shared__ float sdsq[64];
    __shared__ float scw[64];

    const int tid = threadIdx.x;
    const int lane = tid & 63, w = tid >> 6;
    const int li = lane & 15, lg = lane >> 4;
    const int tile = blockIdx.x;

    // phase 0: wave 0, lane = edge: endpoints + relpos (kept in regs for phase 7)
    float rx = 0.f, ry = 0.f, rz = 0.f;
    int r_e = 0;
    if (tid < 64) {
        const int2 rc = sorted_rc[tile * 64 + tid];
        r_e = rc.x;
        rx = pos[3 * rc.x + 0] - pos[3 * rc.y + 0];
        ry = pos[3 * rc.x + 1] - pos[3 * rc.y + 1];
        rz = pos[3 * rc.x + 2] - pos[3 * rc.y + 2];
        sre[tid] = rc.x;
        sce[tid] = rc.y;
        sdsq[tid] = rx * rx + ry * ry + rz * rz;
    }

    // per-lane chunk constants: 8 lanes per edge-row, 8 channels per lane
    const int c8 = lane & 7;   // channel chunk (channels 8*c8 .. 8*c8+7)
    const int eo = lane >> 3;  // edge offset within group of 8

    // dist-weight slice for this lane's channels (two float4 global loads)
    float w1d8[8];
    {
        const float* wd = We1 + 128 * 64 + c8 * 8;
        const float4 wa = *(const float4*)wd;
        const float4 wb = *(const float4*)(wd + 4);
        w1d8[0] = wa.x; w1d8[1] = wa.y; w1d8[2] = wa.z; w1d8[3] = wa.w;
        w1d8[4] = wb.x; w1d8[5] = wb.y; w1d8[6] = wb.z; w1d8[7] = wb.w;
    }

    float be2v[4], bc1v[4], wc2v[4];
#pragma unroll
    for (int ni = 0; ni < 4; ++ni) {
        be2v[ni] = be2[ni * 16 + li];
        bc1v[ni] = bc1[ni * 16 + li];
        wc2v[ni] = Wc2[ni * 16 + li];
    }
    const float bc2s = bc2[0];
    __syncthreads();

    // phase 2: wave w stages m for edges [e0, e0+16): each lane computes 8
    // channels of one edge from 16B chunks of a1r/a1c (dwordx4 gathers).
    const int e0 = w * 16;
#pragma unroll
    for (int hh = 0; hh < 2; ++hh) {
        const int e = e0 + hh * 8 + eo;
        const int re = sre[e];
        const int ce = sce[e];
        const float dv = sdsq[e];
        const bf16x8 ar = *(const bf16x8*)(a1r + (size_t)re * 64 + c8 * 8);
        const bf16x8 ac = *(const bf16x8*)(a1c + (size_t)ce * 64 + c8 * 8);
        bf16x8 out;
#pragma unroll
        for (int j = 0; j < 8; ++j) {
            const float m = b2f((unsigned short)ar[j]) + b2f((unsigned short)ac[j])
                          + dv * w1d8[j];
            out[j] = (short)f2b(silu_f(m));
        }
        *(bf16x8*)&sA[e][c8 * 8] = out;  // ds_write_b128, 16B aligned
    }

    // phase 3: GEMM2 (msg_pre = m @ We2), 16 rows per wave
    f32x4 acc[4];
#pragma unroll
    for (int ni = 0; ni < 4; ++ni) acc[ni] = (f32x4)(0.0f);
#pragma unroll
    for (int ks = 0; ks < 2; ++ks) {
        const bf16x8 af = *(const bf16x8*)&sA[e0 + li][ks * 32 + (lg << 3)];
#pragma unroll
        for (int ni = 0; ni < 4; ++ni) {
            const bf16x8 bf = *(const bf16x8*)(wfrag + (size_t)(ks * 4 + ni) * 512 + lane * 8);
            acc[ni] = MFMA16(af, bf, acc[ni]);
        }
    }

    // phase 4: msg = silu(msg_pre + be2) -> sA [edge][chan] (own rows)
#pragma unroll
    for (int ni = 0; ni < 4; ++ni)
#pragma unroll
        for (int reg = 0; reg < 4; ++reg)
            sA[e0 + lg * 4 + reg][ni * 16 + li] = f2b(silu_f(acc[ni][reg] + be2v[ni]));

    // phase 5: msg quarter-sweep (rows non-decreasing; wave-uniform branch)
    {
        float macc = 0.0f;
        int pr = sre[e0];
#pragma unroll
        for (int j = 0; j < 16; ++j) {
            const int re = sre[e0 + j];
            if (re != pr) {
                atomicAdd(&msg_agg[(size_t)pr * 64 + lane], macc);
                macc = 0.0f;
                pr = re;
            }
            macc += b2f(sA[e0 + j][lane]);
        }
        atomicAdd(&msg_agg[(size_t)pr * 64 + lane], macc);
    }

    // phase 6: GEMM3 (t = msg @ Wc1)
    f32x4 a3[4];
#pragma unroll
    for (int ni = 0; ni < 4; ++ni) a3[ni] = (f32x4)(0.0f);
#pragma unroll
    for (int ks = 0; ks < 2; ++ks) {
        const bf16x8 af = *(const bf16x8*)&sA[e0 + li][ks * 32 + (lg << 3)];
#pragma unroll
        for (int ni = 0; ni < 4; ++ni) {
            const bf16x8 bf = *(const bf16x8*)(wfrag + (size_t)(8 + ks * 4 + ni) * 512 + lane * 8);
            a3[ni] = MFMA16(af, bf, a3[ni]);
        }
    }

    // epilogue: cw[edge] = sum_c silu(t+bc1)[c] * Wc2[c]; reduce over li lanes
    float sv[4];
#pragma unroll
    for (int reg = 0; reg < 4; ++reg) {
        float s = 0.0f;
#pragma unroll
        for (int ni = 0; ni < 4; ++ni)
            s += silu_f(a3[ni][reg] + bc1v[ni]) * wc2v[ni];
        sv[reg] = s;
    }
#pragma unroll
    for (int m = 1; m < 16; m <<= 1)
#pragma unroll
        for (int reg = 0; reg < 4; ++reg) sv[reg] += __shfl_xor(sv[reg], m, 64);
    if (li == 0) {
        float4 cv = make_float4(sv[0] + bc2s, sv[1] + bc2s, sv[2] + bc2s, sv[3] + bc2s);
        *(float4*)&scw[e0 + lg * 4] = cv;
    }
    __syncthreads();

    // phase 7: coord aggregation, wave 0 only. Rows are sorted -> segmented
    // inclusive scan over 64 lanes; last lane of each run flushes one atomic
    // triplet (~5 per tile instead of 192).
    if (tid < 64) {
        const float cw = scw[tid];
        float vx = rx * cw, vy = ry * cw, vz = rz * cw;
#pragma unroll
        for (int d = 1; d < 64; d <<= 1) {
            const float ox = __shfl_up(vx, d, 64);
            const float oy = __shfl_up(vy, d, 64);
            const float oz = __shfl_up(vz, d, 64);
            const int   orr = __shfl_up(r_e, d, 64);
            const bool add = (tid >= d) && (orr == r_e);
            vx += add ? ox : 0.0f;
            vy += add ? oy : 0.0f;
            vz += add ? oz : 0.0f;
        }
        const int rnext = __shfl_down(r_e, 1, 64);
        const bool last = (tid == 63) || (rnext != r_e);
        if (last) {
            atomicAdd(&pos_out[r_e * 3 + 0], vx);
            atomicAdd(&pos_out[r_e * 3 + 1], vy);
            atomicAdd(&pos_out[r_e * 3 + 2], vz);
        }
    }
}

// ---------------- K5: node MLP ----------------

__global__ __launch_bounds__(256, 2) void node_kernel(
    const float* __restrict__ h, const float* __restrict__ msg_agg,
    const unsigned short* __restrict__ wfrag,
    const float* __restrict__ bn1, const float* __restrict__ bn2,
    float* __restrict__ h_out)
{
    __shared__ __align__(16) unsigned short sA[4][64][136];
    const int tid = threadIdx.x;
    const int lane = tid & 63, w = tid >> 6;
    const int t = blockIdx.x * 4 + w;
    const int li = lane & 15, lg = lane >> 4;

    float bn1v[4], bn2v[4];
#pragma unroll
    for (int ni = 0; ni < 4; ++ni) {
        bn1v[ni] = bn1[ni * 16 + li];
        bn2v[ni] = bn2[ni * 16 + li];
    }

    // staging: lane handles float4 chunk c4 of row (pass*4 + rseg)
    const int rseg = lane >> 4;      // 0..3
    const int c4 = lane & 15;        // float4 chunk 0..15
#pragma unroll 4
    for (int pass = 0; pass < 16; ++pass) {
        const int n_loc = pass * 4 + rseg;
        const int n = t * 64 + n_loc;
        float4 hv = make_float4(0.f, 0.f, 0.f, 0.f);
        float4 mv = make_float4(0.f, 0.f, 0.f, 0.f);
        if (n < NN) {
            hv = *(const float4*)&h[(size_t)n * 64 + c4 * 4];
            mv = *(const float4*)&msg_agg[(size_t)n * 64 + c4 * 4];
        }
        typedef __attribute__((ext_vector_type(4))) short bf16x4;
        bf16x4 hp, mp;
        hp[0] = (short)f2b(hv.x); hp[1] = (short)f2b(hv.y);
        hp[2] = (short)f2b(hv.z); hp[3] = (short)f2b(hv.w);
        mp[0] = (short)f2b(mv.x); mp[1] = (short)f2b(mv.y);
        mp[2] = (short)f2b(mv.z); mp[3] = (short)f2b(mv.w);
        *(bf16x4*)&sA[w][n_loc][c4 * 4] = hp;        // ds_write_b64
        *(bf16x4*)&sA[w][n_loc][64 + c4 * 4] = mp;   // ds_write_b64
    }

    // GEMM1: K=128
    f32x4 acc[4][4];
#pragma unroll
    for (int mi = 0; mi < 4; ++mi)
#pragma unroll
        for (int ni = 0; ni < 4; ++ni) acc[mi][ni] = (f32x4)(0.0f);
#pragma unroll
    for (int ks = 0; ks < 4; ++ks) {
        bf16x8 bfr[4], afr[4];
#pragma unroll
        for (int ni = 0; ni < 4; ++ni)
            bfr[ni] = *(const bf16x8*)(wfrag + (size_t)(16 + ks * 4 + ni) * 512 + lane * 8);
#pragma unroll
        for (int mi = 0; mi < 4; ++mi)
            afr[mi] = *(const bf16x8*)&sA[w][mi * 16 + li][ks * 32 + (lg << 3)];
#pragma unroll
        for (int ni = 0; ni < 4; ++ni)
#pragma unroll
            for (int mi = 0; mi < 4; ++mi)
                acc[mi][ni] = MFMA16(afr[mi], bfr[ni], acc[mi][ni]);
    }
    // silu + bn1 -> sA cols 0..63 (own rows)
#pragma unroll
    for (int mi = 0; mi < 4; ++mi)
#pragma unroll
        for (int ni = 0; ni < 4; ++ni)
#pragma unroll
            for (int reg = 0; reg < 4; ++reg)
                sA[w][mi * 16 + lg * 4 + reg][ni * 16 + li] = f2b(silu_f(acc[mi][ni][reg] + bn1v[ni]));

    // GEMM2: K=64
    f32x4 a2[4][4];
#pragma unroll
    for (int mi = 0; mi < 4; ++mi)
#pragma unroll
        for (int ni = 0; ni < 4; ++ni) a2[mi][ni] = (f32x4)(0.0f);
#pragma unroll
    for (int ks = 0; ks < 2; ++ks) {
        bf16x8 bfr[4], afr[4];
#pragma unroll
        for (int ni = 0; ni < 4; ++ni)
            bfr[ni] = *(const bf16x8*)(wfrag + (size_t)(32 + ks * 4 + ni) * 512 + lane * 8);
#pragma unroll
        for (int mi = 0; mi < 4; ++mi)
            afr[mi] = *(const bf16x8*)&sA[w][mi * 16 + li][ks * 32 + (lg << 3)];
#pragma unroll
        for (int ni = 0; ni < 4; ++ni)
#pragma unroll
            for (int mi = 0; mi < 4; ++mi)
                a2[mi][ni] = MFMA16(afr[mi], bfr[ni], a2[mi][ni]);
    }
#pragma unroll
    for (int mi = 0; mi < 4; ++mi)
#pragma unroll
        for (int ni = 0; ni < 4; ++ni)
#pragma unroll
            for (int reg = 0; reg < 4; ++reg) {
                const int n = t * 64 + mi * 16 + lg * 4 + reg;
                if (n < NN) h_out[(size_t)n * 64 + ni * 16 + li] = a2[mi][ni][reg] + bn2v[ni];
            }
}

// ---------------- launch ----------------

extern "C" void kernel_launch(void* const* d_in, const int* in_sizes, int n_in,
                              void* d_out, int out_size, void* d_ws, size_t ws_size,
                              hipStream_t stream) {
    const float* h   = (const float*)d_in[0];
    const float* pos = (const float*)d_in[1];
    const int*   ei  = (const int*)d_in[2];
    const float* We1 = (const float*)d_in[3];
    const float* be1 = (const float*)d_in[4];
    const float* We2 = (const float*)d_in[5];
    const float* be2 = (const float*)d_in[6];
    const float* Wc1 = (const float*)d_in[7];
    const float* bc1 = (const float*)d_in[8];
    const float* Wc2 = (const float*)d_in[9];
    const float* bc2 = (const float*)d_in[10];
    const float* Wn1 = (const float*)d_in[11];
    const float* bn1 = (const float*)d_in[12];
    const float* Wn2 = (const float*)d_in[13];
    const float* bn2 = (const float*)d_in[14];

    unsigned short* a1r   = (unsigned short*)d_ws;            // [N*64] bf16
    unsigned short* a1c   = a1r + (size_t)NN * 64;            // [N*64] bf16
    unsigned short* wfrag = a1c + (size_t)NN * 64;            // 40 frags * 512
    int2* sorted_rc = (int2*)(wfrag + 40 * 512);              // [E]
    int*  cursor    = (int*)(sorted_rc + NE);                 // [SCAN_PAD]

    float* msg_agg = (float*)d_out;                           // reused as h_out
    float* pos_out = msg_agg + (size_t)NN * 64;

    hipMemsetAsync(cursor, 0, (size_t)SCAN_PAD * sizeof(int), stream);
    prep_kernel<<<K1_GRID, 256, 0, stream>>>(h, pos, ei, We1, be1, We2, Wc1, Wn1, Wn2,
                                             a1r, a1c, wfrag, cursor, msg_agg, pos_out);
    scan_kernel<<<1, 1024, 0, stream>>>(cursor);
    scatter_kernel<<<1024, 256, 0, stream>>>(ei, cursor, sorted_rc);
    egnn_edge_kernel<<<ETILE, 256, 0, stream>>>(pos, sorted_rc, a1r, a1c, We1, wfrag,
                                                be2, bc1, Wc2, bc2, msg_agg, pos_out);
    node_kernel<<<196, 256, 0, stream>>>(h, msg_agg, wfrag, bn1, bn2, msg_agg);
}

// Round 6
// 303.811 us; speedup vs baseline: 21.3967x; 1.1009x over previous
//
#include <hip/hip_runtime.h>

// EGNN conv: N=50000, E=800000, C=64.
// Round 6: (a) node_pre role rebuilt — float4 h staging, per-wave LDS transpose
// so a1r/a1c writeback is coalesced dwordx4 (kills 64B-line RMW amplification:
// prep WRITE_SIZE 61MB -> ~30MB predicted); (b) pos4 float4 table so edge
// endpoint gathers are 2 dwordx4 instead of 6 scalar loads.
// Round-5 evidence: prep 88us @ 2% VALU / 18% Occ / 864 GB/s — latency +
// write-amp bound, not BW; edge < 88us (out of top-5).

#define NN 50000
#define NE 800000
#define ETILE 12500         // NE/64
#define SCAN_PAD 53248      // 1024*52

typedef __attribute__((ext_vector_type(8))) short bf16x8;
typedef __attribute__((ext_vector_type(4))) short bf16x4;
typedef __attribute__((ext_vector_type(4))) float f32x4;

#define MFMA16(a, b, c) __builtin_amdgcn_mfma_f32_16x16x32_bf16(a, b, c, 0, 0, 0)

__device__ __forceinline__ unsigned short f2b(float x) {
    union { float f; unsigned u; } v; v.f = x;
    return (unsigned short)((v.u + 0x8000u) >> 16);  // round-half-up (<=0.5 ulp)
}
__device__ __forceinline__ float b2f(unsigned short b) {
    union { unsigned u; float f; } v; v.u = ((unsigned)b) << 16; return v.f;
}
__device__ __forceinline__ float silu_f(float x) {
    return x * __builtin_amdgcn_rcpf(1.0f + __expf(-x));
}

// ---------------- K1: fused prep (block-split roles) ----------------

#define B_NPRE 196
#define B_FRAG 10
#define B_HIST 1024
#define B_ZERO 200
#define B_COPY 16
#define K1_GRID (B_NPRE + B_FRAG + B_HIST + B_ZERO + B_COPY)

__global__ __launch_bounds__(256, 3) void prep_kernel(
    const float* __restrict__ h, const float* __restrict__ pos,
    const int* __restrict__ ei,
    const float* __restrict__ We1, const float* __restrict__ be1,
    const float* __restrict__ We2, const float* __restrict__ Wc1,
    const float* __restrict__ Wn1, const float* __restrict__ Wn2,
    unsigned short* __restrict__ a1r, unsigned short* __restrict__ a1c,
    unsigned short* __restrict__ wfrag, int* __restrict__ cursor,
    float* __restrict__ msg_agg, float* __restrict__ pos_out,
    float4* __restrict__ pos4)
{
    __shared__ __align__(16) unsigned short sH[4][64][72];   // h tile (bf16)
    __shared__ __align__(16) unsigned short sT[4][16][72];   // per-wave transpose buf
    const int b = blockIdx.x;
    const int tid = threadIdx.x;
    const int lane = tid & 63, w = tid >> 6;
    const int li = lane & 15, lg = lane >> 4;

    if (b < B_NPRE) {
        // ---- node_pre: a1r = h@We1[0:64]+be1, a1c = h@We1[64:128] (bf16) ----
        const int t = b * 4 + w;
        float be1v[4];
#pragma unroll
        for (int ni = 0; ni < 4; ++ni) be1v[ni] = be1[ni * 16 + li];

        // stage h as bf16 via float4 loads (coalesced, 16 passes)
        const int rseg = lane >> 4, c4 = lane & 15;
#pragma unroll 4
        for (int pass = 0; pass < 16; ++pass) {
            const int n_loc = pass * 4 + rseg;
            const int n = t * 64 + n_loc;
            float4 hv = make_float4(0.f, 0.f, 0.f, 0.f);
            if (n < NN) hv = *(const float4*)&h[(size_t)n * 64 + c4 * 4];
            bf16x4 hp;
            hp[0] = (short)f2b(hv.x); hp[1] = (short)f2b(hv.y);
            hp[2] = (short)f2b(hv.z); hp[3] = (short)f2b(hv.w);
            *(bf16x4*)&sH[w][n_loc][c4 * 4] = hp;  // ds_write_b64
        }
        __syncthreads();

#pragma unroll
        for (int half = 0; half < 2; ++half) {
            const float* W = We1 + half * 64 * 64;
            unsigned short* out = half ? a1c : a1r;
            f32x4 acc[4][4];
#pragma unroll
            for (int mi = 0; mi < 4; ++mi)
#pragma unroll
                for (int ni = 0; ni < 4; ++ni) acc[mi][ni] = (f32x4)(0.0f);
#pragma unroll
            for (int ks = 0; ks < 2; ++ks) {
                bf16x8 bfr[4], afr[4];
#pragma unroll
                for (int ni = 0; ni < 4; ++ni) {
                    const int n = ni * 16 + li;
                    const int kb = ks * 32 + (lg << 3);
                    bf16x8 v;
#pragma unroll
                    for (int j = 0; j < 8; ++j) v[j] = (short)f2b(W[(kb + j) * 64 + n]);
                    bfr[ni] = v;
                }
#pragma unroll
                for (int mi = 0; mi < 4; ++mi)
                    afr[mi] = *(const bf16x8*)&sH[w][mi * 16 + li][ks * 32 + (lg << 3)];
#pragma unroll
                for (int ni = 0; ni < 4; ++ni)
#pragma unroll
                    for (int mi = 0; mi < 4; ++mi)
                        acc[mi][ni] = MFMA16(afr[mi], bfr[ni], acc[mi][ni]);
            }
            // coalesced writeback: per-mi transpose through wave-private sT,
            // then b128 LDS reads + dwordx4 global stores (full 64B lines).
#pragma unroll
            for (int mi = 0; mi < 4; ++mi) {
#pragma unroll
                for (int ni = 0; ni < 4; ++ni)
#pragma unroll
                    for (int reg = 0; reg < 4; ++reg) {
                        const float bias = half ? 0.0f : be1v[ni];
                        sT[w][lg * 4 + reg][ni * 16 + li] = f2b(acc[mi][ni][reg] + bias);
                    }
#pragma unroll
                for (int pass = 0; pass < 2; ++pass) {
                    const int rr = pass * 8 + (lane >> 3);
                    const int n = t * 64 + mi * 16 + rr;
                    const bf16x8 v = *(const bf16x8*)&sT[w][rr][(lane & 7) * 8];
                    if (n < NN) *(bf16x8*)&out[(size_t)n * 64 + (lane & 7) * 8] = v;
                }
            }
        }
    } else if (b < B_NPRE + B_FRAG) {
        // ---- B-frag table: We2 f=0..7, Wc1 8..15, Wn1 16..31, Wn2 32..39 ----
        const int f = (b - B_NPRE) * 4 + w;
        const float* W;
        int g;
        if (f < 8)       { W = We2; g = f; }
        else if (f < 16) { W = Wc1; g = f - 8; }
        else if (f < 32) { W = Wn1; g = f - 16; }
        else             { W = Wn2; g = f - 32; }
        const int ks = g >> 2, ni = g & 3;
        const int n = ni * 16 + li;
        const int kb = ks * 32 + (lg << 3);
        bf16x8 v;
#pragma unroll
        for (int j = 0; j < 8; ++j) v[j] = (short)f2b(W[(kb + j) * 64 + n]);
        *(bf16x8*)(wfrag + (size_t)f * 512 + lane * 8) = v;
    } else if (b < B_NPRE + B_FRAG + B_HIST) {
        // ---- hist: deg[row]++ ----
        int i = (b - B_NPRE - B_FRAG) * 256 + tid;
        for (; i < NE; i += B_HIST * 256) atomicAdd(&cursor[ei[i]], 1);
    } else if (b < B_NPRE + B_FRAG + B_HIST + B_ZERO) {
        // ---- msg_agg = 0 (float4) ----
        float4* dst = (float4*)msg_agg;
        int i = (b - B_NPRE - B_FRAG - B_HIST) * 256 + tid;
        for (; i < NN * 16; i += B_ZERO * 256) dst[i] = make_float4(0.f, 0.f, 0.f, 0.f);
    } else {
        // ---- pos_out = pos (float4) + pos4 table build ----
        int i = (b - B_NPRE - B_FRAG - B_HIST - B_ZERO) * 256 + tid;
        for (; i < 37500 + NN; i += B_COPY * 256) {
            if (i < 37500) {
                ((float4*)pos_out)[i] = ((const float4*)pos)[i];
            } else {
                const int n = i - 37500;
                pos4[n] = make_float4(pos[3 * n], pos[3 * n + 1], pos[3 * n + 2], 0.f);
            }
        }
    }
}

// ---------------- K2: single-block scan (int4 loads), in-place ----------------

__global__ void scan_kernel(int* __restrict__ cur) {
    __shared__ int part[1024];
    const int t = threadIdx.x;
    int4 v[13];
    const int4* src = (const int4*)cur + t * 13;
#pragma unroll
    for (int i = 0; i < 13; ++i) v[i] = src[i];
    int local[52];
#pragma unroll
    for (int i = 0; i < 13; ++i) {
        local[4 * i + 0] = v[i].x; local[4 * i + 1] = v[i].y;
        local[4 * i + 2] = v[i].z; local[4 * i + 3] = v[i].w;
    }
    int s = 0;
#pragma unroll
    for (int i = 0; i < 52; ++i) s += local[i];
    part[t] = s;
    __syncthreads();
    for (int d = 1; d < 1024; d <<= 1) {
        int pv = (t >= d) ? part[t - d] : 0;
        __syncthreads();
        part[t] += pv;
        __syncthreads();
    }
    int run = part[t] - s;
    const int base = t * 52;
#pragma unroll
    for (int i = 0; i < 52; ++i) {
        const int idx = base + i;
        if (idx < NN) cur[idx] = run;
        run += local[i];
    }
}

// ---------------- K3: scatter (packed int2) ----------------

__global__ void scatter_kernel(const int* __restrict__ ei, int* __restrict__ cursor,
                               int2* __restrict__ sorted_rc) {
    int i = blockIdx.x * blockDim.x + threadIdx.x;
    const int stride = gridDim.x * blockDim.x;
    for (; i < NE; i += stride) {
        const int r = ei[i];
        const int c = ei[NE + i];
        const int p = atomicAdd(&cursor[r], 1);
        sorted_rc[p] = make_int2(r, c);
    }
}

// ---------------- K4: edge kernel, one 64-edge tile per block ----------------

__global__ __launch_bounds__(256, 6) void egnn_edge_kernel(
    const float4* __restrict__ pos4, const int2* __restrict__ sorted_rc,
    const unsigned short* __restrict__ a1r, const unsigned short* __restrict__ a1c,
    const float* __restrict__ We1,  // row 128 = dist weights
    const unsigned short* __restrict__ wfrag,
    const float* __restrict__ be2, const float* __restrict__ bc1,
    const float* __restrict__ Wc2, const float* __restrict__ bc2,
    float* __restrict__ msg_agg, float* __restrict__ pos_out)
{
    __shared__ __align__(16) unsigned short sA[64][80];  // [edge][chan]
    __shared__ int sre[64];
    __shared__ int sce[64];
    __shared__ float sdsq[64];
    __shared__ float scw[64];

    const int tid = threadIdx.x;
    const int lane = tid & 63, w = tid >> 6;
    const int li = lane & 15, lg = lane >> 4;
    const int tile = blockIdx.x;

    // phase 0: wave 0, lane = edge: endpoints + relpos via pos4 (2 dwordx4 gathers)
    float rx = 0.f, ry = 0.f, rz = 0.f;
    int r_e = 0;
    if (tid < 64) {
        const int2 rc = sorted_rc[tile * 64 + tid];
        r_e = rc.x;
        const float4 pr = pos4[rc.x];
        const float4 pc = pos4[rc.y];
        rx = pr.x - pc.x;
        ry = pr.y - pc.y;
        rz = pr.z - pc.z;
        sre[tid] = rc.x;
        sce[tid] = rc.y;
        sdsq[tid] = rx * rx + ry * ry + rz * rz;
    }

    // per-lane chunk constants: 8 lanes per edge-row, 8 channels per lane
    const int c8 = lane & 7;   // channel chunk (channels 8*c8 .. 8*c8+7)
    const int eo = lane >> 3;  // edge offset within group of 8

    float w1d8[8];
    {
        const float* wd = We1 + 128 * 64 + c8 * 8;
        const float4 wa = *(const float4*)wd;
        const float4 wb = *(const float4*)(wd + 4);
        w1d8[0] = wa.x; w1d8[1] = wa.y; w1d8[2] = wa.z; w1d8[3] = wa.w;
        w1d8[4] = wb.x; w1d8[5] = wb.y; w1d8[6] = wb.z; w1d8[7] = wb.w;
    }

    float be2v[4], bc1v[4], wc2v[4];
#pragma unroll
    for (int ni = 0; ni < 4; ++ni) {
        be2v[ni] = be2[ni * 16 + li];
        bc1v[ni] = bc1[ni * 16 + li];
        wc2v[ni] = Wc2[ni * 16 + li];
    }
    const float bc2s = bc2[0];
    __syncthreads();

    // phase 2: wave w stages m for edges [e0, e0+16): each lane computes 8
    // channels of one edge from 16B chunks of a1r/a1c (dwordx4 gathers).
    const int e0 = w * 16;
#pragma unroll
    for (int hh = 0; hh < 2; ++hh) {
        const int e = e0 + hh * 8 + eo;
        const int re = sre[e];
        const int ce = sce[e];
        const float dv = sdsq[e];
        const bf16x8 ar = *(const bf16x8*)(a1r + (size_t)re * 64 + c8 * 8);
        const bf16x8 ac = *(const bf16x8*)(a1c + (size_t)ce * 64 + c8 * 8);
        bf16x8 out;
#pragma unroll
        for (int j = 0; j < 8; ++j) {
            const float m = b2f((unsigned short)ar[j]) + b2f((unsigned short)ac[j])
                          + dv * w1d8[j];
            out[j] = (short)f2b(silu_f(m));
        }
        *(bf16x8*)&sA[e][c8 * 8] = out;  // ds_write_b128
    }

    // phase 3: GEMM2 (msg_pre = m @ We2), 16 rows per wave
    f32x4 acc[4];
#pragma unroll
    for (int ni = 0; ni < 4; ++ni) acc[ni] = (f32x4)(0.0f);
#pragma unroll
    for (int ks = 0; ks < 2; ++ks) {
        const bf16x8 af = *(const bf16x8*)&sA[e0 + li][ks * 32 + (lg << 3)];
#pragma unroll
        for (int ni = 0; ni < 4; ++ni) {
            const bf16x8 bf = *(const bf16x8*)(wfrag + (size_t)(ks * 4 + ni) * 512 + lane * 8);
            acc[ni] = MFMA16(af, bf, acc[ni]);
        }
    }

    // phase 4: msg = silu(msg_pre + be2) -> sA [edge][chan] (own rows)
#pragma unroll
    for (int ni = 0; ni < 4; ++ni)
#pragma unroll
        for (int reg = 0; reg < 4; ++reg)
            sA[e0 + lg * 4 + reg][ni * 16 + li] = f2b(silu_f(acc[ni][reg] + be2v[ni]));

    // phase 5: msg quarter-sweep (rows non-decreasing; wave-uniform branch)
    {
        float macc = 0.0f;
        int pr = sre[e0];
#pragma unroll
        for (int j = 0; j < 16; ++j) {
            const int re = sre[e0 + j];
            if (re != pr) {
                atomicAdd(&msg_agg[(size_t)pr * 64 + lane], macc);
                macc = 0.0f;
                pr = re;
            }
            macc += b2f(sA[e0 + j][lane]);
        }
        atomicAdd(&msg_agg[(size_t)pr * 64 + lane], macc);
    }

    // phase 6: GEMM3 (t = msg @ Wc1)
    f32x4 a3[4];
#pragma unroll
    for (int ni = 0; ni < 4; ++ni) a3[ni] = (f32x4)(0.0f);
#pragma unroll
    for (int ks = 0; ks < 2; ++ks) {
        const bf16x8 af = *(const bf16x8*)&sA[e0 + li][ks * 32 + (lg << 3)];
#pragma unroll
        for (int ni = 0; ni < 4; ++ni) {
            const bf16x8 bf = *(const bf16x8*)(wfrag + (size_t)(8 + ks * 4 + ni) * 512 + lane * 8);
            a3[ni] = MFMA16(af, bf, a3[ni]);
        }
    }

    // epilogue: cw[edge] = sum_c silu(t+bc1)[c] * Wc2[c]; reduce over li lanes
    float sv[4];
#pragma unroll
    for (int reg = 0; reg < 4; ++reg) {
        float s = 0.0f;
#pragma unroll
        for (int ni = 0; ni < 4; ++ni)
            s += silu_f(a3[ni][reg] + bc1v[ni]) * wc2v[ni];
        sv[reg] = s;
    }
#pragma unroll
    for (int m = 1; m < 16; m <<= 1)
#pragma unroll
        for (int reg = 0; reg < 4; ++reg) sv[reg] += __shfl_xor(sv[reg], m, 64);
    if (li == 0) {
        float4 cv = make_float4(sv[0] + bc2s, sv[1] + bc2s, sv[2] + bc2s, sv[3] + bc2s);
        *(float4*)&scw[e0 + lg * 4] = cv;
    }
    __syncthreads();

    // phase 7: coord aggregation, wave 0: segmented scan, 1 atomic triplet/run
    if (tid < 64) {
        const float cw = scw[tid];
        float vx = rx * cw, vy = ry * cw, vz = rz * cw;
#pragma unroll
        for (int d = 1; d < 64; d <<= 1) {
            const float ox = __shfl_up(vx, d, 64);
            const float oy = __shfl_up(vy, d, 64);
            const float oz = __shfl_up(vz, d, 64);
            const int   orr = __shfl_up(r_e, d, 64);
            const bool add = (tid >= d) && (orr == r_e);
            vx += add ? ox : 0.0f;
            vy += add ? oy : 0.0f;
            vz += add ? oz : 0.0f;
        }
        const int rnext = __shfl_down(r_e, 1, 64);
        const bool last = (tid == 63) || (rnext != r_e);
        if (last) {
            atomicAdd(&pos_out[r_e * 3 + 0], vx);
            atomicAdd(&pos_out[r_e * 3 + 1], vy);
            atomicAdd(&pos_out[r_e * 3 + 2], vz);
        }
    }
}

// ---------------- K5: node MLP ----------------

__global__ __launch_bounds__(256, 2) void node_kernel(
    const float* __restrict__ h, const float* __restrict__ msg_agg,
    const unsigned short* __restrict__ wfrag,
    const float* __restrict__ bn1, const float* __restrict__ bn2,
    float* __restrict__ h_out)
{
    __shared__ __align__(16) unsigned short sA[4][64][136];
    const int tid = threadIdx.x;
    const int lane = tid & 63, w = tid >> 6;
    const int t = blockIdx.x * 4 + w;
    const int li = lane & 15, lg = lane >> 4;

    float bn1v[4], bn2v[4];
#pragma unroll
    for (int ni = 0; ni < 4; ++ni) {
        bn1v[ni] = bn1[ni * 16 + li];
        bn2v[ni] = bn2[ni * 16 + li];
    }

    const int rseg = lane >> 4;      // 0..3
    const int c4 = lane & 15;        // float4 chunk 0..15
#pragma unroll 4
    for (int pass = 0; pass < 16; ++pass) {
        const int n_loc = pass * 4 + rseg;
        const int n = t * 64 + n_loc;
        float4 hv = make_float4(0.f, 0.f, 0.f, 0.f);
        float4 mv = make_float4(0.f, 0.f, 0.f, 0.f);
        if (n < NN) {
            hv = *(const float4*)&h[(size_t)n * 64 + c4 * 4];
            mv = *(const float4*)&msg_agg[(size_t)n * 64 + c4 * 4];
        }
        bf16x4 hp, mp;
        hp[0] = (short)f2b(hv.x); hp[1] = (short)f2b(hv.y);
        hp[2] = (short)f2b(hv.z); hp[3] = (short)f2b(hv.w);
        mp[0] = (short)f2b(mv.x); mp[1] = (short)f2b(mv.y);
        mp[2] = (short)f2b(mv.z); mp[3] = (short)f2b(mv.w);
        *(bf16x4*)&sA[w][n_loc][c4 * 4] = hp;
        *(bf16x4*)&sA[w][n_loc][64 + c4 * 4] = mp;
    }

    // GEMM1: K=128
    f32x4 acc[4][4];
#pragma unroll
    for (int mi = 0; mi < 4; ++mi)
#pragma unroll
        for (int ni = 0; ni < 4; ++ni) acc[mi][ni] = (f32x4)(0.0f);
#pragma unroll
    for (int ks = 0; ks < 4; ++ks) {
        bf16x8 bfr[4], afr[4];
#pragma unroll
        for (int ni = 0; ni < 4; ++ni)
            bfr[ni] = *(const bf16x8*)(wfrag + (size_t)(16 + ks * 4 + ni) * 512 + lane * 8);
#pragma unroll
        for (int mi = 0; mi < 4; ++mi)
            afr[mi] = *(const bf16x8*)&sA[w][mi * 16 + li][ks * 32 + (lg << 3)];
#pragma unroll
        for (int ni = 0; ni < 4; ++ni)
#pragma unroll
            for (int mi = 0; mi < 4; ++mi)
                acc[mi][ni] = MFMA16(afr[mi], bfr[ni], acc[mi][ni]);
    }
    // silu + bn1 -> sA cols 0..63 (own rows)
#pragma unroll
    for (int mi = 0; mi < 4; ++mi)
#pragma unroll
        for (int ni = 0; ni < 4; ++ni)
#pragma unroll
            for (int reg = 0; reg < 4; ++reg)
                sA[w][mi * 16 + lg * 4 + reg][ni * 16 + li] = f2b(silu_f(acc[mi][ni][reg] + bn1v[ni]));

    // GEMM2: K=64
    f32x4 a2[4][4];
#pragma unroll
    for (int mi = 0; mi < 4; ++mi)
#pragma unroll
        for (int ni = 0; ni < 4; ++ni) a2[mi][ni] = (f32x4)(0.0f);
#pragma unroll
    for (int ks = 0; ks < 2; ++ks) {
        bf16x8 bfr[4], afr[4];
#pragma unroll
        for (int ni = 0; ni < 4; ++ni)
            bfr[ni] = *(const bf16x8*)(wfrag + (size_t)(32 + ks * 4 + ni) * 512 + lane * 8);
#pragma unroll
        for (int mi = 0; mi < 4; ++mi)
            afr[mi] = *(const bf16x8*)&sA[w][mi * 16 + li][ks * 32 + (lg << 3)];
#pragma unroll
        for (int ni = 0; ni < 4; ++ni)
#pragma unroll
            for (int mi = 0; mi < 4; ++mi)
                a2[mi][ni] = MFMA16(afr[mi], bfr[ni], a2[mi][ni]);
    }
#pragma unroll
    for (int mi = 0; mi < 4; ++mi)
#pragma unroll
        for (int ni = 0; ni < 4; ++ni)
#pragma unroll
            for (int reg = 0; reg < 4; ++reg) {
                const int n = t * 64 + mi * 16 + lg * 4 + reg;
                if (n < NN) h_out[(size_t)n * 64 + ni * 16 + li] = a2[mi][ni][reg] + bn2v[ni];
            }
}

// ---------------- launch ----------------

extern "C" void kernel_launch(void* const* d_in, const int* in_sizes, int n_in,
                              void* d_out, int out_size, void* d_ws, size_t ws_size,
                              hipStream_t stream) {
    const float* h   = (const float*)d_in[0];
    const float* pos = (const float*)d_in[1];
    const int*   ei  = (const int*)d_in[2];
    const float* We1 = (const float*)d_in[3];
    const float* be1 = (const float*)d_in[4];
    const float* We2 = (const float*)d_in[5];
    const float* be2 = (const float*)d_in[6];
    const float* Wc1 = (const float*)d_in[7];
    const float* bc1 = (const float*)d_in[8];
    const float* Wc2 = (const float*)d_in[9];
    const float* bc2 = (const float*)d_in[10];
    const float* Wn1 = (const float*)d_in[11];
    const float* bn1 = (const float*)d_in[12];
    const float* Wn2 = (const float*)d_in[13];
    const float* bn2 = (const float*)d_in[14];

    unsigned short* a1r   = (unsigned short*)d_ws;            // [N*64] bf16
    unsigned short* a1c   = a1r + (size_t)NN * 64;            // [N*64] bf16
    unsigned short* wfrag = a1c + (size_t)NN * 64;            // 40 frags * 512
    int2* sorted_rc = (int2*)(wfrag + 40 * 512);              // [E]
    int*  cursor    = (int*)(sorted_rc + NE);                 // [SCAN_PAD]
    float4* pos4    = (float4*)(cursor + SCAN_PAD);           // [N]

    float* msg_agg = (float*)d_out;                           // reused as h_out
    float* pos_out = msg_agg + (size_t)NN * 64;

    hipMemsetAsync(cursor, 0, (size_t)SCAN_PAD * sizeof(int), stream);
    prep_kernel<<<K1_GRID, 256, 0, stream>>>(h, pos, ei, We1, be1, We2, Wc1, Wn1, Wn2,
                                             a1r, a1c, wfrag, cursor, msg_agg, pos_out,
                                             pos4);
    scan_kernel<<<1, 1024, 0, stream>>>(cursor);
    scatter_kernel<<<1024, 256, 0, stream>>>(ei, cursor, sorted_rc);
    egnn_edge_kernel<<<ETILE, 256, 0, stream>>>(pos4, sorted_rc, a1r, a1c, We1, wfrag,
                                                be2, bc1, Wc2, bc2, msg_agg, pos_out);
    node_kernel<<<196, 256, 0, stream>>>(h, msg_agg, wfrag, bn1, bn2, msg_agg);
}

// Round 7
// 301.762 us; speedup vs baseline: 21.5420x; 1.0068x over previous
//
#include <hip/hip_runtime.h>

// EGNN conv: N=50000, E=800000, C=64.
// Round 7: pipeline overlap. K1 = hist || frag-table(all weights incl We1) ||
// msg_agg-zero || pos copy/pos4; K2 = shfl-scan (2 barriers); K3 = scatter ||
// node_pre (fused, node_pre overlaps scatter); edge phase-0 parallelized over
// 4 waves + single barrier; node_pre/node re-tiled to 782 blocks (1 tile/blk).
// Round-6 evidence: edge 71us @ VALU 76% (= transcendental floor ~50-55us);
// total 304 => ~230us hides in serialized prep/scan/scatter/node + launches.

#define NN 50000
#define NE 800000
#define ETILE 12500         // NE/64
#define SCAN_PAD 53248      // 1024*52

typedef __attribute__((ext_vector_type(8))) short bf16x8;
typedef __attribute__((ext_vector_type(4))) short bf16x4;
typedef __attribute__((ext_vector_type(4))) float f32x4;

#define MFMA16(a, b, c) __builtin_amdgcn_mfma_f32_16x16x32_bf16(a, b, c, 0, 0, 0)

__device__ __forceinline__ unsigned short f2b(float x) {
    union { float f; unsigned u; } v; v.f = x;
    return (unsigned short)((v.u + 0x8000u) >> 16);
}
__device__ __forceinline__ float b2f(unsigned short b) {
    union { unsigned u; float f; } v; v.u = ((unsigned)b) << 16; return v.f;
}
__device__ __forceinline__ float silu_f(float x) {
    return x * __builtin_amdgcn_rcpf(1.0f + __expf(-x));
}

// wfrag layout (56 frags x 512 bf16): 0..7 We2, 8..15 Wc1, 16..31 Wn1,
// 32..39 Wn2, 40..47 We1[0:64], 48..55 We1[64:128].

// ---------------- K1: hist || frag || zero || copy (block-split) ----------------

#define B1_HIST 1024
#define B1_FRAG 14
#define B1_ZERO 200
#define B1_COPY 16
#define K1_GRID (B1_HIST + B1_FRAG + B1_ZERO + B1_COPY)

__global__ __launch_bounds__(256, 4) void prep1_kernel(
    const int* __restrict__ ei, const float* __restrict__ pos,
    const float* __restrict__ We1, const float* __restrict__ We2,
    const float* __restrict__ Wc1, const float* __restrict__ Wn1,
    const float* __restrict__ Wn2,
    unsigned short* __restrict__ wfrag, int* __restrict__ cursor,
    float* __restrict__ msg_agg, float* __restrict__ pos_out,
    float4* __restrict__ pos4)
{
    const int b = blockIdx.x, tid = threadIdx.x;
    if (b < B1_HIST) {
        int i = b * 256 + tid;
        for (; i < NE; i += B1_HIST * 256) atomicAdd(&cursor[ei[i]], 1);
    } else if (b < B1_HIST + B1_FRAG) {
        const int lane = tid & 63, w = tid >> 6;
        const int li = lane & 15, lg = lane >> 4;
        const int f = (b - B1_HIST) * 4 + w;  // 0..55
        const float* W; int g;
        if (f < 8)       { W = We2; g = f; }
        else if (f < 16) { W = Wc1; g = f - 8; }
        else if (f < 32) { W = Wn1; g = f - 16; }
        else if (f < 40) { W = Wn2; g = f - 32; }
        else if (f < 48) { W = We1; g = f - 40; }
        else             { W = We1 + 64 * 64; g = f - 48; }
        const int ks = g >> 2, ni = g & 3;
        const int n = ni * 16 + li, kb = ks * 32 + (lg << 3);
        bf16x8 v;
#pragma unroll
        for (int j = 0; j < 8; ++j) v[j] = (short)f2b(W[(kb + j) * 64 + n]);
        *(bf16x8*)(wfrag + (size_t)f * 512 + lane * 8) = v;
    } else if (b < B1_HIST + B1_FRAG + B1_ZERO) {
        float4* dst = (float4*)msg_agg;
        int i = (b - B1_HIST - B1_FRAG) * 256 + tid;
        for (; i < NN * 16; i += B1_ZERO * 256) dst[i] = make_float4(0.f, 0.f, 0.f, 0.f);
    } else {
        int i = (b - B1_HIST - B1_FRAG - B1_ZERO) * 256 + tid;
        for (; i < 37500 + NN; i += B1_COPY * 256) {
            if (i < 37500) {
                ((float4*)pos_out)[i] = ((const float4*)pos)[i];
            } else {
                const int n = i - 37500;
                pos4[n] = make_float4(pos[3 * n], pos[3 * n + 1], pos[3 * n + 2], 0.f);
            }
        }
    }
}

// ---------------- K2: single-block scan (shfl wave-scan, 2 barriers) ----------------

__global__ void scan_kernel(int* __restrict__ cur) {
    __shared__ int wsum[16];
    const int t = threadIdx.x;
    const int lane = t & 63, wid = t >> 6;
    int4 v[13];
    const int4* src = (const int4*)cur + t * 13;
#pragma unroll
    for (int i = 0; i < 13; ++i) v[i] = src[i];
    int local[52];
#pragma unroll
    for (int i = 0; i < 13; ++i) {
        local[4 * i + 0] = v[i].x; local[4 * i + 1] = v[i].y;
        local[4 * i + 2] = v[i].z; local[4 * i + 3] = v[i].w;
    }
    int s = 0;
#pragma unroll
    for (int i = 0; i < 52; ++i) s += local[i];
    // inclusive shfl scan over the wave
    int inc = s;
#pragma unroll
    for (int d = 1; d < 64; d <<= 1) {
        const int o = __shfl_up(inc, d, 64);
        if (lane >= d) inc += o;
    }
    if (lane == 63) wsum[wid] = inc;
    __syncthreads();
    if (t == 0) {
        int run = 0;
#pragma unroll
        for (int i = 0; i < 16; ++i) { const int tmp = wsum[i]; wsum[i] = run; run += tmp; }
    }
    __syncthreads();
    int run = wsum[wid] + inc - s;  // exclusive prefix of this thread's chunk
    const int base = t * 52;
#pragma unroll
    for (int i = 0; i < 52; ++i) {
        const int idx = base + i;
        if (idx < NN) cur[idx] = run;
        run += local[i];
    }
}

// ---------------- K3: node_pre || scatter (block-split) ----------------

#define B3_NPRE 782
#define B3_SCAT 512
#define K3_GRID (B3_NPRE + B3_SCAT)

__global__ __launch_bounds__(256, 4) void prep2_kernel(
    const float* __restrict__ h, const float* __restrict__ be1,
    const int* __restrict__ ei, int* __restrict__ cursor,
    const unsigned short* __restrict__ wfrag,
    unsigned short* __restrict__ a1r, unsigned short* __restrict__ a1c,
    int2* __restrict__ sorted_rc)
{
    __shared__ __align__(16) unsigned short sH[64][72];
    __shared__ __align__(16) unsigned short sT[4][16][72];
    const int b = blockIdx.x, tid = threadIdx.x;
    if (b < B3_NPRE) {
        // one 64-node tile per block; wave w owns rows [w*16, w*16+16)
        const int lane = tid & 63, w = tid >> 6;
        const int li = lane & 15, lg = lane >> 4;
        const int t = b;
        const int c4 = lane & 15, rsub = lane >> 4;
#pragma unroll
        for (int pass = 0; pass < 4; ++pass) {
            const int n_loc = w * 16 + pass * 4 + rsub;
            const int n = t * 64 + n_loc;
            float4 hv = make_float4(0.f, 0.f, 0.f, 0.f);
            if (n < NN) hv = *(const float4*)&h[(size_t)n * 64 + c4 * 4];
            bf16x4 hp;
            hp[0] = (short)f2b(hv.x); hp[1] = (short)f2b(hv.y);
            hp[2] = (short)f2b(hv.z); hp[3] = (short)f2b(hv.w);
            *(bf16x4*)&sH[n_loc][c4 * 4] = hp;   // wave-private rows
        }
        float be1v[4];
#pragma unroll
        for (int ni = 0; ni < 4; ++ni) be1v[ni] = be1[ni * 16 + li];

#pragma unroll
        for (int half = 0; half < 2; ++half) {
            unsigned short* out = half ? a1c : a1r;
            f32x4 acc[4];
#pragma unroll
            for (int ni = 0; ni < 4; ++ni) acc[ni] = (f32x4)(0.0f);
#pragma unroll
            for (int ks = 0; ks < 2; ++ks) {
                const bf16x8 afr = *(const bf16x8*)&sH[w * 16 + li][ks * 32 + (lg << 3)];
#pragma unroll
                for (int ni = 0; ni < 4; ++ni) {
                    const bf16x8 bfr = *(const bf16x8*)(wfrag +
                        (size_t)(40 + half * 8 + ks * 4 + ni) * 512 + lane * 8);
                    acc[ni] = MFMA16(afr, bfr, acc[ni]);
                }
            }
            // transpose via wave-private sT, then coalesced dwordx4 stores
#pragma unroll
            for (int ni = 0; ni < 4; ++ni)
#pragma unroll
                for (int reg = 0; reg < 4; ++reg)
                    sT[w][lg * 4 + reg][ni * 16 + li] =
                        f2b(acc[ni][reg] + (half ? 0.f : be1v[ni]));
#pragma unroll
            for (int pass = 0; pass < 2; ++pass) {
                const int rr = pass * 8 + (lane >> 3);
                const int n = t * 64 + w * 16 + rr;
                const bf16x8 v = *(const bf16x8*)&sT[w][rr][(lane & 7) * 8];
                if (n < NN) *(bf16x8*)&out[(size_t)n * 64 + (lane & 7) * 8] = v;
            }
        }
    } else {
        int i = (b - B3_NPRE) * 256 + tid;
        for (; i < NE; i += B3_SCAT * 256) {
            const int r = ei[i];
            const int c = ei[NE + i];
            const int p = atomicAdd(&cursor[r], 1);
            sorted_rc[p] = make_int2(r, c);
        }
    }
}

// ---------------- K4: edge kernel, one 64-edge tile per block ----------------

__global__ __launch_bounds__(256, 6) void egnn_edge_kernel(
    const float4* __restrict__ pos4, const int2* __restrict__ sorted_rc,
    const unsigned short* __restrict__ a1r, const unsigned short* __restrict__ a1c,
    const float* __restrict__ We1,  // row 128 = dist weights
    const unsigned short* __restrict__ wfrag,
    const float* __restrict__ be2, const float* __restrict__ bc1,
    const float* __restrict__ Wc2, const float* __restrict__ bc2,
    float* __restrict__ msg_agg, float* __restrict__ pos_out)
{
    __shared__ __align__(16) unsigned short sA[64][80];  // [edge][chan]
    __shared__ __align__(8) int2 srce[64];               // (row,col)
    __shared__ __align__(16) float4 sdr[64];             // (rx,ry,rz,dsq)
    __shared__ float scw[64];

    const int tid = threadIdx.x;
    const int lane = tid & 63, w = tid >> 6;
    const int li = lane & 15, lg = lane >> 4;
    const int tile = blockIdx.x;
    const int e0 = w * 16;

    // phase 0 (per wave, lanes 0-15): endpoints + relpos for own 16 edges
    if (lane < 16) {
        const int e = e0 + lane;
        const int2 rc = sorted_rc[tile * 64 + e];
        const float4 pr = pos4[rc.x];
        const float4 pc = pos4[rc.y];
        const float rx = pr.x - pc.x, ry = pr.y - pc.y, rz = pr.z - pc.z;
        srce[e] = rc;
        sdr[e] = make_float4(rx, ry, rz, rx * rx + ry * ry + rz * rz);
    }

    const int c8 = lane & 7;   // channel chunk
    const int eo = lane >> 3;  // edge offset within group of 8

    float w1d8[8];
    {
        const float* wd = We1 + 128 * 64 + c8 * 8;
        const float4 wa = *(const float4*)wd;
        const float4 wb = *(const float4*)(wd + 4);
        w1d8[0] = wa.x; w1d8[1] = wa.y; w1d8[2] = wa.z; w1d8[3] = wa.w;
        w1d8[4] = wb.x; w1d8[5] = wb.y; w1d8[6] = wb.z; w1d8[7] = wb.w;
    }
    float be2v[4], bc1v[4], wc2v[4];
#pragma unroll
    for (int ni = 0; ni < 4; ++ni) {
        be2v[ni] = be2[ni * 16 + li];
        bc1v[ni] = bc1[ni * 16 + li];
        wc2v[ni] = Wc2[ni * 16 + li];
    }
    const float bc2s = bc2[0];

    // phase 2: stage m for own 16 edges (same-wave LDS rows; no barrier needed)
#pragma unroll
    for (int hh = 0; hh < 2; ++hh) {
        const int e = e0 + hh * 8 + eo;
        const int2 rc = srce[e];
        const float dv = sdr[e].w;
        const bf16x8 ar = *(const bf16x8*)(a1r + (size_t)rc.x * 64 + c8 * 8);
        const bf16x8 ac = *(const bf16x8*)(a1c + (size_t)rc.y * 64 + c8 * 8);
        bf16x8 out;
#pragma unroll
        for (int j = 0; j < 8; ++j) {
            const float m = b2f((unsigned short)ar[j]) + b2f((unsigned short)ac[j])
                          + dv * w1d8[j];
            out[j] = (short)f2b(silu_f(m));
        }
        *(bf16x8*)&sA[e][c8 * 8] = out;
    }

    // phase 3: GEMM2 (msg_pre = m @ We2)
    f32x4 acc[4];
#pragma unroll
    for (int ni = 0; ni < 4; ++ni) acc[ni] = (f32x4)(0.0f);
#pragma unroll
    for (int ks = 0; ks < 2; ++ks) {
        const bf16x8 af = *(const bf16x8*)&sA[e0 + li][ks * 32 + (lg << 3)];
#pragma unroll
        for (int ni = 0; ni < 4; ++ni) {
            const bf16x8 bf = *(const bf16x8*)(wfrag + (size_t)(ks * 4 + ni) * 512 + lane * 8);
            acc[ni] = MFMA16(af, bf, acc[ni]);
        }
    }

    // phase 4: msg = silu(msg_pre + be2) -> sA (own rows)
#pragma unroll
    for (int ni = 0; ni < 4; ++ni)
#pragma unroll
        for (int reg = 0; reg < 4; ++reg)
            sA[e0 + lg * 4 + reg][ni * 16 + li] = f2b(silu_f(acc[ni][reg] + be2v[ni]));

    // phase 5: msg quarter-sweep (rows non-decreasing)
    {
        float macc = 0.0f;
        int pr = srce[e0].x;
#pragma unroll
        for (int j = 0; j < 16; ++j) {
            const int re = srce[e0 + j].x;
            if (re != pr) {
                atomicAdd(&msg_agg[(size_t)pr * 64 + lane], macc);
                macc = 0.0f;
                pr = re;
            }
            macc += b2f(sA[e0 + j][lane]);
        }
        atomicAdd(&msg_agg[(size_t)pr * 64 + lane], macc);
    }

    // phase 6: GEMM3 (t = msg @ Wc1)
    f32x4 a3[4];
#pragma unroll
    for (int ni = 0; ni < 4; ++ni) a3[ni] = (f32x4)(0.0f);
#pragma unroll
    for (int ks = 0; ks < 2; ++ks) {
        const bf16x8 af = *(const bf16x8*)&sA[e0 + li][ks * 32 + (lg << 3)];
#pragma unroll
        for (int ni = 0; ni < 4; ++ni) {
            const bf16x8 bf = *(const bf16x8*)(wfrag + (size_t)(8 + ks * 4 + ni) * 512 + lane * 8);
            a3[ni] = MFMA16(af, bf, a3[ni]);
        }
    }

    // epilogue: cw[edge] = sum_c silu(t+bc1)[c] * Wc2[c]
    float sv[4];
#pragma unroll
    for (int reg = 0; reg < 4; ++reg) {
        float s = 0.0f;
#pragma unroll
        for (int ni = 0; ni < 4; ++ni)
            s += silu_f(a3[ni][reg] + bc1v[ni]) * wc2v[ni];
        sv[reg] = s;
    }
#pragma unroll
    for (int m = 1; m < 16; m <<= 1)
#pragma unroll
        for (int reg = 0; reg < 4; ++reg) sv[reg] += __shfl_xor(sv[reg], m, 64);
    if (li == 0) {
        float4 cv = make_float4(sv[0] + bc2s, sv[1] + bc2s, sv[2] + bc2s, sv[3] + bc2s);
        *(float4*)&scw[e0 + lg * 4] = cv;
    }
    __syncthreads();  // the only block barrier: publishes srce/sdr/scw to wave 0

    // phase 7: coord aggregation (wave 0): segmented scan, 1 atomic triplet/run
    if (tid < 64) {
        const float4 dr = sdr[tid];
        const int r_e = srce[tid].x;
        const float cw = scw[tid];
        float vx = dr.x * cw, vy = dr.y * cw, vz = dr.z * cw;
#pragma unroll
        for (int d = 1; d < 64; d <<= 1) {
            const float ox = __shfl_up(vx, d, 64);
            const float oy = __shfl_up(vy, d, 64);
            const float oz = __shfl_up(vz, d, 64);
            const int   orr = __shfl_up(r_e, d, 64);
            const bool add = (tid >= d) && (orr == r_e);
            vx += add ? ox : 0.0f;
            vy += add ? oy : 0.0f;
            vz += add ? oz : 0.0f;
        }
        const int rnext = __shfl_down(r_e, 1, 64);
        const bool last = (tid == 63) || (rnext != r_e);
        if (last) {
            atomicAdd(&pos_out[r_e * 3 + 0], vx);
            atomicAdd(&pos_out[r_e * 3 + 1], vy);
            atomicAdd(&pos_out[r_e * 3 + 2], vz);
        }
    }
}

// ---------------- K5: node MLP (one 64-node tile per block) ----------------

__global__ __launch_bounds__(256, 4) void node_kernel(
    const float* __restrict__ h, const float* __restrict__ msg_agg,
    const unsigned short* __restrict__ wfrag,
    const float* __restrict__ bn1, const float* __restrict__ bn2,
    float* __restrict__ h_out)
{
    __shared__ __align__(16) unsigned short sA[64][136];
    const int tid = threadIdx.x;
    const int lane = tid & 63, w = tid >> 6;
    const int t = blockIdx.x;
    const int li = lane & 15, lg = lane >> 4;

    float bn1v[4], bn2v[4];
#pragma unroll
    for (int ni = 0; ni < 4; ++ni) {
        bn1v[ni] = bn1[ni * 16 + li];
        bn2v[ni] = bn2[ni * 16 + li];
    }

    // stage own 16 rows of [h | msg] (K=128): cols 0-63 h, 64-127 msg
#pragma unroll
    for (int pass = 0; pass < 8; ++pass) {
        const int idx = pass * 64 + lane;          // 0..511
        const int n_loc = w * 16 + (idx >> 5);     // own rows
        const int c4 = idx & 31;                   // float4 chunk 0..31
        const int n = t * 64 + n_loc;
        float4 v = make_float4(0.f, 0.f, 0.f, 0.f);
        if (n < NN) {
            const float* src = (c4 < 16) ? &h[(size_t)n * 64 + c4 * 4]
                                         : &msg_agg[(size_t)n * 64 + (c4 - 16) * 4];
            v = *(const float4*)src;
        }
        bf16x4 p;
        p[0] = (short)f2b(v.x); p[1] = (short)f2b(v.y);
        p[2] = (short)f2b(v.z); p[3] = (short)f2b(v.w);
        *(bf16x4*)&sA[n_loc][c4 * 4] = p;
    }

    // GEMM1: K=128
    f32x4 acc[4];
#pragma unroll
    for (int ni = 0; ni < 4; ++ni) acc[ni] = (f32x4)(0.0f);
#pragma unroll
    for (int ks = 0; ks < 4; ++ks) {
        const bf16x8 afr = *(const bf16x8*)&sA[w * 16 + li][ks * 32 + (lg << 3)];
#pragma unroll
        for (int ni = 0; ni < 4; ++ni) {
            const bf16x8 bfr = *(const bf16x8*)(wfrag + (size_t)(16 + ks * 4 + ni) * 512 + lane * 8);
            acc[ni] = MFMA16(afr, bfr, acc[ni]);
        }
    }
    // silu + bn1 -> sA cols 0..63 (own rows)
#pragma unroll
    for (int ni = 0; ni < 4; ++ni)
#pragma unroll
        for (int reg = 0; reg < 4; ++reg)
            sA[w * 16 + lg * 4 + reg][ni * 16 + li] = f2b(silu_f(acc[ni][reg] + bn1v[ni]));

    // GEMM2: K=64
    f32x4 a2[4];
#pragma unroll
    for (int ni = 0; ni < 4; ++ni) a2[ni] = (f32x4)(0.0f);
#pragma unroll
    for (int ks = 0; ks < 2; ++ks) {
        const bf16x8 afr = *(const bf16x8*)&sA[w * 16 + li][ks * 32 + (lg << 3)];
#pragma unroll
        for (int ni = 0; ni < 4; ++ni) {
            const bf16x8 bfr = *(const bf16x8*)(wfrag + (size_t)(32 + ks * 4 + ni) * 512 + lane * 8);
            a2[ni] = MFMA16(afr, bfr, a2[ni]);
        }
    }
#pragma unroll
    for (int ni = 0; ni < 4; ++ni)
#pragma unroll
        for (int reg = 0; reg < 4; ++reg) {
            const int n = t * 64 + w * 16 + lg * 4 + reg;
            if (n < NN) h_out[(size_t)n * 64 + ni * 16 + li] = a2[ni][reg] + bn2v[ni];
        }
}

// ---------------- launch ----------------

extern "C" void kernel_launch(void* const* d_in, const int* in_sizes, int n_in,
                              void* d_out, int out_size, void* d_ws, size_t ws_size,
                              hipStream_t stream) {
    const float* h   = (const float*)d_in[0];
    const float* pos = (const float*)d_in[1];
    const int*   ei  = (const int*)d_in[2];
    const float* We1 = (const float*)d_in[3];
    const float* be1 = (const float*)d_in[4];
    const float* We2 = (const float*)d_in[5];
    const float* be2 = (const float*)d_in[6];
    const float* Wc1 = (const float*)d_in[7];
    const float* bc1 = (const float*)d_in[8];
    const float* Wc2 = (const float*)d_in[9];
    const float* bc2 = (const float*)d_in[10];
    const float* Wn1 = (const float*)d_in[11];
    const float* bn1 = (const float*)d_in[12];
    const float* Wn2 = (const float*)d_in[13];
    const float* bn2 = (const float*)d_in[14];

    unsigned short* a1r   = (unsigned short*)d_ws;            // [N*64] bf16
    unsigned short* a1c   = a1r + (size_t)NN * 64;            // [N*64] bf16
    unsigned short* wfrag = a1c + (size_t)NN * 64;            // 56 frags * 512
    int2* sorted_rc = (int2*)(wfrag + 56 * 512);              // [E]
    int*  cursor    = (int*)(sorted_rc + NE);                 // [SCAN_PAD]
    float4* pos4    = (float4*)(cursor + SCAN_PAD);           // [N]

    float* msg_agg = (float*)d_out;                           // reused as h_out
    float* pos_out = msg_agg + (size_t)NN * 64;

    hipMemsetAsync(cursor, 0, (size_t)SCAN_PAD * sizeof(int), stream);
    prep1_kernel<<<K1_GRID, 256, 0, stream>>>(ei, pos, We1, We2, Wc1, Wn1, Wn2,
                                              wfrag, cursor, msg_agg, pos_out, pos4);
    scan_kernel<<<1, 1024, 0, stream>>>(cursor);
    prep2_kernel<<<K3_GRID, 256, 0, stream>>>(h, be1, ei, cursor, wfrag,
                                              a1r, a1c, sorted_rc);
    egnn_edge_kernel<<<ETILE, 256, 0, stream>>>(pos4, sorted_rc, a1r, a1c, We1, wfrag,
                                                be2, bc1, Wc2, bc2, msg_agg, pos_out);
    node_kernel<<<782, 256, 0, stream>>>(h, msg_agg, wfrag, bn1, bn2, msg_agg);
}